// Round 9
// baseline (252.668 us; speedup 1.0000x reference)
//
#include <hip/hip_runtime.h>

#define BDIM 2
#define SEQ  1568
#define DIM  768
#define NH   12
#define FR   8
#define NTOK 196
#define HD   64
#define MTOT (BDIM*SEQ)   // 3136 token rows
#define M2   (MTOT*FR)    // 25088 (t,f) rows

typedef __attribute__((ext_vector_type(8))) short s16x8;
typedef __attribute__((ext_vector_type(4))) float f32x4;
typedef __attribute__((ext_vector_type(16))) float f32x16;
typedef __attribute__((ext_vector_type(4))) int i32x4;

static __device__ __forceinline__ float bf2f(ushort u) {
  return __uint_as_float(((unsigned)u) << 16);
}
static __device__ __forceinline__ ushort f2bf(float f) {
  unsigned u = __float_as_uint(f);
  unsigned r = (u + 0x7fffu + ((u >> 16) & 1u)) >> 16;
  return (ushort)r;
}
static __device__ __forceinline__ f32x4 mfma16(s16x8 a, s16x8 b, f32x4 c) {
  return __builtin_amdgcn_mfma_f32_16x16x32_bf16(a, b, c, 0, 0, 0);
}
static __device__ __forceinline__ f32x16 mfma32(s16x8 a, s16x8 b, f32x16 c) {
  return __builtin_amdgcn_mfma_f32_32x32x16_bf16(a, b, c, 0, 0, 0);
}
static __device__ __forceinline__ int cvtpk(float lo, float hi) {
  int r;
  asm("v_cvt_pk_bf16_f32 %0, %1, %2" : "=v"(r) : "v"(lo), "v"(hi));
  return r;
}
static __device__ __forceinline__ void gload_lds16(const ushort* g, ushort* l) {
  __builtin_amdgcn_global_load_lds(
      (const __attribute__((address_space(1))) void*)g,
      (__attribute__((address_space(3))) void*)l, 16, 0, 0);
}

// ---------------------------------------------------------------------------
// Fused convert: inputs -> bf16, 4 weights transposed -> bf16, and straight
// bf16 copies of the Wpkv halves (Wpk_bf, Wpv_bf) for the qw / Wcomb paths.
// grid: 4704 input + 1152 transpose (nx24 x ky12 x wid4) + 1152 straight.
// ---------------------------------------------------------------------------
__global__ __launch_bounds__(256)
void cvt_all(const float* __restrict__ xq, const float* __restrict__ xk,
             ushort* __restrict__ xqbf, ushort* __restrict__ xkbf,
             const float* __restrict__ Wq, const float* __restrict__ Wkv,
             const float* __restrict__ Wpq, const float* __restrict__ Wproj,
             const float* __restrict__ Wpkv,
             ushort* __restrict__ WqT, ushort* __restrict__ WkvT,
             ushort* __restrict__ WpqT, ushort* __restrict__ WprT,
             ushort* __restrict__ Wpk_bf, ushort* __restrict__ Wpv_bf,
             int n4) {
  __shared__ float T[64][65];
  const int blk = blockIdx.x;
  const int tid = threadIdx.x;

  if (blk < 4704) {             // input conversion
    int i = blk*256 + tid;
    const float* src; ushort* dst; int j;
    if (i < n4)        { src = xq; dst = xqbf; j = i; }
    else               { src = xk; dst = xkbf; j = i - n4; }
    float4 v = ((const float4*)src)[j];
    ushort4 o; o.x = f2bf(v.x); o.y = f2bf(v.y); o.z = f2bf(v.z); o.w = f2bf(v.w);
    ((ushort4*)dst)[j] = o;
    return;
  }

  if (blk < 5856) {             // weight transpose (4 weights)
    int idx = blk - 4704;
    const int wid = idx / 288; idx %= 288;
    const int ky = idx / 24;
    const int nx = idx % 24;
    const float* W; ushort* WT; int N;
    switch (wid) {
      case 0: W = Wq;    WT = WqT;   N = DIM;   break;
      case 1: W = Wkv;   WT = WkvT;  N = 2*DIM; break;
      case 2: W = Wpq;   WT = WpqT;  N = DIM;   break;
      default: W = Wproj; WT = WprT; N = DIM;   break;
    }
    if (nx >= N/64) return;
    #pragma unroll
    for (int it = 0; it < 4; it++) {
      int id2 = it*256 + tid;
      int r = id2 >> 4, c4 = (id2 & 15) << 2;
      float4 v = *(const float4*)&W[(size_t)(ky*64 + r)*N + nx*64 + c4];
      T[r][c4+0] = v.x; T[r][c4+1] = v.y; T[r][c4+2] = v.z; T[r][c4+3] = v.w;
    }
    __syncthreads();
    #pragma unroll
    for (int it = 0; it < 4; it++) {
      int id2 = it*256 + tid;
      int n = id2 >> 4, k4 = (id2 & 15) << 2;
      ushort4 o;
      o.x = f2bf(T[k4+0][n]); o.y = f2bf(T[k4+1][n]);
      o.z = f2bf(T[k4+2][n]); o.w = f2bf(T[k4+3][n]);
      *(ushort4*)&WT[(size_t)(nx*64 + n)*DIM + ky*64 + k4] = o;
    }
    return;
  }

  // straight bf16 copies of Wpkv halves: Wpk_bf / Wpv_bf [768][768]
  {
    int id2 = blk - 5856;            // 0..1151
    int half = id2 / 576;
    int e = (id2 % 576)*256 + tid;   // float4 index within 768x768
    int r = e / 192;
    int c4 = (e % 192) * 4;
    float4 v = *(const float4*)&Wpkv[(size_t)r*(2*DIM) + half*DIM + c4];
    ushort4 o; o.x = f2bf(v.x); o.y = f2bf(v.y); o.z = f2bf(v.z); o.w = f2bf(v.w);
    ushort* dst = half ? Wpv_bf : Wpk_bf;
    *(ushort4*)&dst[(size_t)r*DIM + c4] = o;
  }
}

// Vt[(b,f,h)][64][224] bf16, zero-padded n>=196. grid = 192
__global__ __launch_bounds__(256)
void vtrans(const ushort* __restrict__ kvbf, ushort* __restrict__ Vt) {
  __shared__ ushort Vl[NTOK][72];
  const int x = blockIdx.x;
  const int h = x % NH, f = (x / NH) % FR, b = x / (NH*FR);
  const int tid = threadIdx.x;
  for (int idx = tid; idx < NTOK*16; idx += 256) {
    int n = idx >> 4, c4 = (idx & 15) << 2;
    const ushort* p = kvbf + (size_t)(b*SEQ + f*NTOK + n)*(2*DIM) + DIM + h*HD + c4;
    *(ushort4*)&Vl[n][c4] = *(const ushort4*)p;
  }
  __syncthreads();
  ushort* vb = Vt + (size_t)x * (HD*224);
  for (int idx = tid; idx < 64*56; idx += 256) {
    int d = idx / 56, n4 = (idx % 56) << 2;
    ushort4 o;
    o.x = (n4+0 < NTOK) ? Vl[n4+0][d] : (ushort)0;
    o.y = (n4+1 < NTOK) ? Vl[n4+1][d] : (ushort)0;
    o.z = (n4+2 < NTOK) ? Vl[n4+2][d] : (ushort)0;
    o.w = (n4+3 < NTOK) ? Vl[n4+3][d] : (ushort)0;
    *(ushort4*)&vb[(size_t)d*224 + n4] = o;
  }
}

// ---------------------------------------------------------------------------
// Merged q+kv projection, 128x128 tiles (gemm_logits staging structure:
// 4 gloads per K-step feed 16 MFMAs/wave — 2x the MFMA/staging ratio of the
// old 128x64 shape at the same VGPR/LDS footprint). grid (18, 25):
// bx<6: qbf = 0.125*(xq@Wq) cols bx*128; else kvbf = xk@Wkv cols (bx-6)*128.
// ---------------------------------------------------------------------------
__global__ __launch_bounds__(256)
void proj_pair(const ushort* __restrict__ xqbf, const ushort* __restrict__ xkbf,
               const ushort* __restrict__ WqT, const ushort* __restrict__ WkvT,
               ushort* __restrict__ qbf, ushort* __restrict__ kvbf)
{
  __shared__ ushort As[128][32];
  __shared__ ushort Bs[128][32];
  const int bx = blockIdx.x, by = blockIdx.y;
  const ushort* A; const ushort* Bt; ushort* C; int N, col0; float scale;
  if (bx < 6) { A = xqbf; Bt = WqT;  C = qbf;  N = DIM;   col0 = bx*128;     scale = 0.125f; }
  else        { A = xkbf; Bt = WkvT; C = kvbf; N = 2*DIM; col0 = (bx-6)*128; scale = 1.0f; }

  const int tid = threadIdx.x;
  const int w = tid >> 6, lane = tid & 63;
  const int lq = lane & 15, quad = lane >> 4;
  const int wr = (w >> 1) * 64, wc = (w & 1) * 64;
  const int lrow = tid >> 2, lcol = (tid & 3) << 3;

  int ar0 = by*128 + lrow;       if (ar0 > MTOT-1) ar0 = MTOT-1;
  int ar1 = by*128 + 64 + lrow;  if (ar1 > MTOT-1) ar1 = MTOT-1;
  const size_t aoff0 = (size_t)ar0*DIM + lcol;
  const size_t aoff1 = (size_t)ar1*DIM + lcol;
  const size_t boff0 = (size_t)(col0 + lrow)*DIM + lcol;
  const size_t boff1 = (size_t)(col0 + 64 + lrow)*DIM + lcol;

  f32x4 acc[4][4] = {};
  for (int k0 = 0; k0 < DIM; k0 += 32) {
    __syncthreads();
    gload_lds16(A  + aoff0 + k0, &As[w*16][0]);
    gload_lds16(A  + aoff1 + k0, &As[64 + w*16][0]);
    gload_lds16(Bt + boff0 + k0, &Bs[w*16][0]);
    gload_lds16(Bt + boff1 + k0, &Bs[64 + w*16][0]);
    __syncthreads();
    s16x8 af[4], bw[4];
    #pragma unroll
    for (int i = 0; i < 4; i++) af[i] = *(const s16x8*)&As[wr + i*16 + lq][quad*8];
    #pragma unroll
    for (int j = 0; j < 4; j++) bw[j] = *(const s16x8*)&Bs[wc + j*16 + lq][quad*8];
    #pragma unroll
    for (int i = 0; i < 4; i++)
      #pragma unroll
      for (int j = 0; j < 4; j++)
        acc[i][j] = mfma16(af[i], bw[j], acc[i][j]);
  }

  #pragma unroll
  for (int i = 0; i < 4; i++) {
    #pragma unroll
    for (int r = 0; r < 4; r++) {
      int row = by*128 + wr + i*16 + quad*4 + r;
      if (row < MTOT) {
        #pragma unroll
        for (int j = 0; j < 4; j++)
          C[(size_t)row*N + col0 + wc + j*16 + lq] = f2bf(acc[i][j][r] * scale);
      }
    }
  }
}

// ---------------------------------------------------------------------------
// Generic 128x128-tile GEMM (R2-proven gemm_logits staging, plain epilogue).
// grid (N/128, ceil(M/128)). K=768. BF16OUT: bf16 C; else float.
// ---------------------------------------------------------------------------
template<bool BIAS, bool BF16OUT>
__global__ __launch_bounds__(256)
void gemm128(const ushort* __restrict__ A, const ushort* __restrict__ Bt,
             void* __restrict__ Cv, const float* __restrict__ bias,
             int M, int N, float scale)
{
  __shared__ ushort As[128][32];
  __shared__ ushort Bs[128][32];
  const int bx = blockIdx.x, by = blockIdx.y;
  const int tid = threadIdx.x;
  const int w = tid >> 6, lane = tid & 63;
  const int lq = lane & 15, quad = lane >> 4;
  const int wr = (w >> 1) * 64, wc = (w & 1) * 64;
  const int lrow = tid >> 2, lcol = (tid & 3) << 3;
  const int col0 = bx*128;

  int ar0 = by*128 + lrow;       if (ar0 > M-1) ar0 = M-1;
  int ar1 = by*128 + 64 + lrow;  if (ar1 > M-1) ar1 = M-1;
  const size_t aoff0 = (size_t)ar0*DIM + lcol;
  const size_t aoff1 = (size_t)ar1*DIM + lcol;
  const size_t boff0 = (size_t)(col0 + lrow)*DIM + lcol;
  const size_t boff1 = (size_t)(col0 + 64 + lrow)*DIM + lcol;

  f32x4 acc[4][4] = {};
  for (int k0 = 0; k0 < DIM; k0 += 32) {
    __syncthreads();
    gload_lds16(A  + aoff0 + k0, &As[w*16][0]);
    gload_lds16(A  + aoff1 + k0, &As[64 + w*16][0]);
    gload_lds16(Bt + boff0 + k0, &Bs[w*16][0]);
    gload_lds16(Bt + boff1 + k0, &Bs[64 + w*16][0]);
    __syncthreads();
    s16x8 af[4], bw[4];
    #pragma unroll
    for (int i = 0; i < 4; i++) af[i] = *(const s16x8*)&As[wr + i*16 + lq][quad*8];
    #pragma unroll
    for (int j = 0; j < 4; j++) bw[j] = *(const s16x8*)&Bs[wc + j*16 + lq][quad*8];
    #pragma unroll
    for (int i = 0; i < 4; i++)
      #pragma unroll
      for (int j = 0; j < 4; j++)
        acc[i][j] = mfma16(af[i], bw[j], acc[i][j]);
  }

  #pragma unroll
  for (int i = 0; i < 4; i++) {
    #pragma unroll
    for (int r = 0; r < 4; r++) {
      int row = by*128 + wr + i*16 + quad*4 + r;
      if (row < M) {
        #pragma unroll
        for (int j = 0; j < 4; j++) {
          int col = col0 + wc + j*16 + lq;
          float v = acc[i][j][r] * scale;
          if (BIAS) v += bias[col];
          if (BF16OUT) ((ushort*)Cv)[(size_t)row*N + col] = f2bf(v);
          else         ((float*)Cv)[(size_t)row*N + col] = v;
        }
      }
    }
  }
}

// ---------------------------------------------------------------------------
// FUSED q2 + qw kernel. grid (12 = head, 25 Mtiles).
// Phase 1: q2 tile = 0.125*(x_diag @ Wpq) cols h*64..+63  (K=768, DIAG gather)
//          -> parked in LDS q2s[128][72] bf16 (same-wave rows only).
// Phase 2: qw[row][h][c] = sum_dd q2[row][dd]*Wpk[c][h*64+dd] for c in 12
//          64-wide tiles (K=64, Bs restaged per 32-chunk, 1 gload/step).
// ---------------------------------------------------------------------------
__global__ __launch_bounds__(256)
void q2qw(const ushort* __restrict__ x, const ushort* __restrict__ WpqT,
          const ushort* __restrict__ Wpk, ushort* __restrict__ qw)
{
  __shared__ ushort As[128][32];
  __shared__ ushort Bs[64][32];
  __shared__ ushort q2s[128][72];
  const int h = blockIdx.x, by = blockIdx.y;
  const int tid = threadIdx.x;
  const int w = tid >> 6, lane = tid & 63;
  const int lq = lane & 15, quad = lane >> 4;
  const int lrow = tid >> 2, lcol = (tid & 3) << 3;

  int ar0 = by*128 + lrow;       if (ar0 > MTOT-1) ar0 = MTOT-1;
  int ar1 = by*128 + 64 + lrow;  if (ar1 > MTOT-1) ar1 = MTOT-1;
  const int f0 = (ar0 % SEQ) / NTOK, f1 = (ar1 % SEQ) / NTOK;
  const size_t aoff0 = ((size_t)ar0*FR + f0)*DIM + lcol;
  const size_t aoff1 = ((size_t)ar1*FR + f1)*DIM + lcol;
  const size_t boff  = (size_t)(h*64 + lrow)*DIM + lcol;

  // ---- phase 1: q2 tile (DIAG A-gather, K=768)
  f32x4 acc[2][4] = {};
  for (int k0 = 0; k0 < DIM; k0 += 32) {
    __syncthreads();
    gload_lds16(x    + aoff0 + k0, &As[w*16][0]);
    gload_lds16(x    + aoff1 + k0, &As[64 + w*16][0]);
    gload_lds16(WpqT + boff  + k0, &Bs[w*16][0]);
    __syncthreads();
    s16x8 af[2], bw[4];
    #pragma unroll
    for (int i = 0; i < 2; i++) af[i] = *(const s16x8*)&As[w*32 + i*16 + lq][quad*8];
    #pragma unroll
    for (int j = 0; j < 4; j++) bw[j] = *(const s16x8*)&Bs[j*16 + lq][quad*8];
    #pragma unroll
    for (int i = 0; i < 2; i++)
      #pragma unroll
      for (int j = 0; j < 4; j++)
        acc[i][j] = mfma16(af[i], bw[j], acc[i][j]);
  }

  // ---- park q2 tile in LDS bf16 (scale 0.125); rows are wave-local
  #pragma unroll
  for (int i = 0; i < 2; i++)
    #pragma unroll
    for (int r = 0; r < 4; r++) {
      int row = w*32 + i*16 + quad*4 + r;
      #pragma unroll
      for (int j = 0; j < 4; j++)
        q2s[row][j*16 + lq] = f2bf(acc[i][j][r] * 0.125f);
    }

  // ---- phase 2: qw tiles over c (12 x 64 cols), K=64 from q2s
  for (int ct = 0; ct < 12; ++ct) {
    f32x4 acc2[2][4] = {};
    #pragma unroll
    for (int k0 = 0; k0 < 64; k0 += 32) {
      __syncthreads();
      gload_lds16(Wpk + (size_t)(ct*64 + lrow)*DIM + h*HD + k0 + lcol, &Bs[w*16][0]);
      __syncthreads();
      s16x8 af[2], bw[4];
      #pragma unroll
      for (int i = 0; i < 2; i++)
        af[i] = *(const s16x8*)&q2s[w*32 + i*16 + lq][k0 + quad*8];
      #pragma unroll
      for (int j = 0; j < 4; j++) bw[j] = *(const s16x8*)&Bs[j*16 + lq][quad*8];
      #pragma unroll
      for (int i = 0; i < 2; i++)
        #pragma unroll
        for (int j = 0; j < 4; j++)
          acc2[i][j] = mfma16(af[i], bw[j], acc2[i][j]);
    }
    #pragma unroll
    for (int i = 0; i < 2; i++) {
      #pragma unroll
      for (int r = 0; r < 4; r++) {
        int row = by*128 + w*32 + i*16 + quad*4 + r;
        if (row < MTOT) {
          #pragma unroll
          for (int j = 0; j < 4; j++)
            qw[(size_t)row*(NH*DIM) + h*DIM + ct*64 + j*16 + lq] = f2bf(acc2[i][j][r]);
        }
      }
    }
  }
}

// ---------------------------------------------------------------------------
// Fused logits + softmax + x-aggregation. grid 784 (4 t / block, 1 t / wave).
// Stages x[4][8][768] and qw[4][12][768] in LDS (264-elem chunks: bank-step
// 12 -> conflict-free A, 2-way B = free). Per wave: 24 MFMA k-steps give
// logits[f=quad*4+r][h=lq]; in-wave softmax over f (one shfl_xor 16);
// writes attn2 and computes xa from the x STILL IN LDS (no global re-read).
// ---------------------------------------------------------------------------
__global__ __launch_bounds__(256)
void logits_sa(const ushort* __restrict__ qw, const ushort* __restrict__ x,
               float* __restrict__ attn2, ushort* __restrict__ xa)
{
  __shared__ ushort xs[4*8*792];    // 49.5 KB  [tf][ch*264+cc]
  __shared__ ushort qws[4*12*792];  // 74.25 KB [th][ch*264+cc]
  __shared__ float  a_s[4][NH][FR]; // 1.5 KB
  const int tid = threadIdx.x;
  const int t0 = blockIdx.x * 4;

  #pragma unroll
  for (int r = 0; r < 12; ++r) {    // stage x: 4t*8f*96 vec8
    int id = r*256 + tid;
    int tf = id / 96, v8 = id % 96;
    int ch = v8 >> 5, cc = v8 & 31;
    s16x8 v = *(const s16x8*)(x + ((size_t)(t0 + (tf >> 3))*FR + (tf & 7))*DIM + v8*8);
    *(s16x8*)&xs[tf*792 + ch*264 + cc*8] = v;
  }
  #pragma unroll
  for (int r = 0; r < 18; ++r) {    // stage qw: 4t*12h*96 vec8
    int id = r*256 + tid;
    int th = id / 96, v8 = id % 96;
    int ch = v8 >> 5, cc = v8 & 31;
    s16x8 v = *(const s16x8*)(qw + (size_t)(t0 + th/12)*(NH*DIM) + (th%12)*DIM + v8*8);
    *(s16x8*)&qws[th*792 + ch*264 + cc*8] = v;
  }
  __syncthreads();

  const int w = tid >> 6, lane = tid & 63;
  const int lq = lane & 15, quad = lane >> 4;
  const int fr = lq & 7;                      // A row (rows 8-15 duplicate f)
  const int hc = (lq < 12) ? lq : 0;          // B col clamp
  f32x4 acc = {};
  #pragma unroll
  for (int ks = 0; ks < 24; ++ks) {
    int ch = ks >> 3, cc = (ks & 7) * 32;
    s16x8 a = *(const s16x8*)&xs[(w*8 + fr)*792 + ch*264 + cc + quad*8];
    s16x8 b = *(const s16x8*)&qws[(w*12 + hc)*792 + ch*264 + cc + quad*8];
    acc = mfma16(a, b, acc);
  }

  // softmax over f: own 4 f's (rows quad*4+r, quad<2) + partner via xor 16
  float m4 = fmaxf(fmaxf(acc[0], acc[1]), fmaxf(acc[2], acc[3]));
  float M = fmaxf(m4, __shfl_xor(m4, 16));
  float e0 = __expf(acc[0]-M), e1 = __expf(acc[1]-M);
  float e2 = __expf(acc[2]-M), e3 = __expf(acc[3]-M);
  float s4 = (e0+e1)+(e2+e3);
  float S = s4 + __shfl_xor(s4, 16);
  float inv = 1.0f / S;
  if (quad < 2 && lq < 12) {
    int gt = t0 + w;
    int b = gt / SEQ, sI = gt % SEQ;
    float4 av; av.x = e0*inv; av.y = e1*inv; av.z = e2*inv; av.w = e3*inv;
    *(float4*)(attn2 + ((size_t)(b*NH + hc)*SEQ + sI)*FR + quad*4) = av;
    a_s[w][hc][quad*4+0] = av.x; a_s[w][hc][quad*4+1] = av.y;
    a_s[w][hc][quad*4+2] = av.z; a_s[w][hc][quad*4+3] = av.w;
  }
  __syncthreads();

  // xa[t,c] = sum_f a_s[t][h(c)][f] * x[t,f,c]; x read from LDS
  #pragma unroll
  for (int it = 0; it < 2; ++it) {
    int id = it*256 + tid;
    if (id < 384) {
      int tt = id / 96, v8 = id % 96;
      int ch = v8 >> 5, cc = v8 & 31;
      int h = v8 >> 3;
      float av[8] = {};
      #pragma unroll
      for (int f = 0; f < FR; ++f) {
        float a = a_s[tt][h][f];
        s16x8 xv = *(const s16x8*)&xs[(tt*8 + f)*792 + ch*264 + cc*8];
        #pragma unroll
        for (int e = 0; e < 8; ++e) av[e] += a * bf2f((ushort)xv[e]);
      }
      ushort4 o0, o1;
      o0.x = f2bf(av[0]); o0.y = f2bf(av[1]); o0.z = f2bf(av[2]); o0.w = f2bf(av[3]);
      o1.x = f2bf(av[4]); o1.y = f2bf(av[5]); o1.z = f2bf(av[6]); o1.w = f2bf(av[7]);
      ushort* op = xa + (size_t)(t0 + tt)*DIM + v8*8;
      *(ushort4*)op = o0; *(ushort4*)(op + 4) = o1;
    }
  }
}

// ---------------------------------------------------------------------------
// Stage 1, 32x32 MFMA, swapped operands (S^T = K.Q^T), in-register P.
// (unchanged from R2-verified version)
// ---------------------------------------------------------------------------
__global__ __launch_bounds__(256)
void stage1_mfma(const ushort* __restrict__ qbf, const ushort* __restrict__ kvbf,
                 const ushort* __restrict__ Vt, ushort* __restrict__ x)
{
  __shared__ ushort sh[208*64];   // 26624 B: K tile, then per-wave X transpose

  const int bh = blockIdx.x;   // 0..23
  const int f  = blockIdx.y;   // 0..7
  const int qt = blockIdx.z;   // 0..12
  const int b = bh / NH, h = bh % NH;
  const int tid = threadIdx.x;
  const int w = tid >> 6, lane = tid & 63;
  const int l31 = lane & 31, hl = lane >> 5;

  const ushort* kbase = kvbf + ((size_t)b*SEQ + f*NTOK)*(2*DIM) + h*HD;
  #pragma unroll
  for (int p = 0; p < 6; ++p) {
    const int c = w*6 + p;                         // 8-row chunk, rows < 192
    const int row = c*8 + (lane >> 3);
    const ushort* src = kbase + (size_t)row*(2*DIM)
                      + (((lane & 7) ^ (lane >> 3)) << 3);
    gload_lds16(src, &sh[c*512]);
  }
  { // rows 192..207: 192..195 from global, 196..207 zero (same swizzle)
    const int row = 192 + (tid >> 4);
    const int c4  = (tid & 15) << 2;
    ushort4 v; v.x = 0; v.y = 0; v.z = 0; v.w = 0;
    if (row < NTOK)
      v = *(const ushort4*)(kbase + (size_t)row*(2*DIM) + c4);
    *(ushort4*)&sh[row*64 + ((((c4 >> 3) ^ (row & 7)) << 3) | (c4 & 7))] = v;
  }

  int qrow = qt*128 + w*32 + l31; if (qrow > SEQ-1) qrow = SEQ-1;
  const ushort* qp = qbf + ((size_t)b*SEQ + qrow)*DIM + h*HD + hl*8;
  const s16x8 bq0 = *(const s16x8*)(qp);
  const s16x8 bq1 = *(const s16x8*)(qp + 16);
  const s16x8 bq2 = *(const s16x8*)(qp + 32);
  const s16x8 bq3 = *(const s16x8*)(qp + 48);

  __syncthreads();

  f32x16 acc[7];
  {
    f32x16 z = {};
    #pragma unroll
    for (int nt = 0; nt < 7; ++nt) acc[nt] = z;
  }
  const int sx = l31 & 7;
  #pragma unroll
  for (int nt = 0; nt < 7; ++nt) {
    const int rl = (nt == 6) ? (l31 & 15) : l31;   // keep tile-6 A-reads in bounds
    const int rbase = (nt*32 + rl)*64;
    acc[nt] = mfma32(*(const s16x8*)&sh[rbase + (((0 + hl) ^ sx) << 3)], bq0, acc[nt]);
    acc[nt] = mfma32(*(const s16x8*)&sh[rbase + (((2 + hl) ^ sx) << 3)], bq1, acc[nt]);
    acc[nt] = mfma32(*(const s16x8*)&sh[rbase + (((4 + hl) ^ sx) << 3)], bq2, acc[nt]);
    acc[nt] = mfma32(*(const s16x8*)&sh[rbase + (((6 + hl) ^ sx) << 3)], bq3, acc[nt]);
  }

  __syncthreads();   // all K reads done -> sh reusable for X transpose

  float s0 = 0.f, s1 = 0.f, s2 = 0.f, s3 = 0.f;
  #pragma unroll
  for (int nt = 0; nt < 7; ++nt) {
    #pragma unroll
    for (int g = 0; g < 16; ++g) {
      float e;
      if (nt == 6) {
        if (g < 4) { e = __expf(acc[6][g]); if (hl) e = 0.f; }  // n=192..195 only
        else e = 0.f;
      } else {
        e = __expf(acc[nt][g]);
      }
      acc[nt][g] = e;
      if ((g & 3) == 0) s0 += e; else if ((g & 3) == 1) s1 += e;
      else if ((g & 3) == 2) s2 += e; else s3 += e;
    }
  }
  float sum = (s0 + s1) + (s2 + s3);
  sum += __shfl_xor(sum, 32);
  const float sinv = 1.0f / sum;

  f32x16 o0, o1;
  { f32x16 z = {}; o0 = z; o1 = z; }
  const ushort* vb = Vt + ((size_t)((b*FR + f)*NH + h)) * (HD*224);
  const ushort* vr0 = vb + (size_t)l31*224 + hl*8;
  const ushort* vr1 = vr0 + 32*224;
  #pragma unroll
  for (int nt = 0; nt < 7; ++nt) {
    #pragma unroll
    for (int kh = 0; kh < 2; ++kh) {
      int w0 = cvtpk(acc[nt][8*kh+0], acc[nt][8*kh+1]);
      int w1 = cvtpk(acc[nt][8*kh+2], acc[nt][8*kh+3]);
      int w2 = cvtpk(acc[nt][8*kh+4], acc[nt][8*kh+5]);
      int w3 = cvtpk(acc[nt][8*kh+6], acc[nt][8*kh+7]);
      asm("v_permlane32_swap_b32 %0, %1" : "+v"(w0), "+v"(w2));
      asm("v_permlane32_swap_b32 %0, %1" : "+v"(w1), "+v"(w3));
      union { i32x4 i; s16x8 s; } u;
      u.i.x = w0; u.i.y = w1; u.i.z = w2; u.i.w = w3;
      const int ks = nt*2 + kh;
      const s16x8 va0 = *(const s16x8*)(vr0 + ks*16);
      const s16x8 va1 = *(const s16x8*)(vr1 + ks*16);
      o0 = mfma32(va0, u.s, o0);
      o1 = mfma32(va1, u.s, o1);
    }
  }

  ushort* XT = sh + w*2048;
  #pragma unroll
  for (int dt = 0; dt < 2; ++dt) {
    #pragma unroll
    for (int c = 0; c < 4; ++c) {
      #pragma unroll
      for (int rp = 0; rp < 2; ++rp) {
        const float lo = (dt ? o1[4*c + 2*rp]     : o0[4*c + 2*rp])     * sinv;
        const float hi = (dt ? o1[4*c + 2*rp + 1] : o0[4*c + 2*rp + 1]) * sinv;
        const int word = cvtpk(lo, hi);
        const int d = dt*32 + 8*c + 4*hl + 2*rp;
        *(uint*)&XT[l31*64 + (((d >> 3) ^ (l31 & 7)) << 3) + (d & 7)] = (uint)word;
      }
    }
  }
  #pragma unroll
  for (int it = 0; it < 4; ++it) {
    const int q = it*8 + (lane >> 3);
    const int g = lane & 7;
    s16x8 xv = *(const s16x8*)&XT[q*64 + ((g ^ (q & 7)) << 3)];
    const int s = qt*128 + w*32 + q;
    if (s < SEQ) {
      ushort* xp = x + (((size_t)b*SEQ + s)*FR + f)*DIM + h*HD + g*8;
      *(s16x8*)xp = xv;
    }
  }
}

// ---------------------------------------------------------------------------
// Workspace (ushort units; ~123 MB used; harness memsets ~268 MB of ws):
//  xbf | kvbf | qbf | xqbf (Vt alias) | xkbf (xa alias) |
//  WqT | WkvT | WpqT | WprT | Wpk_bf | Wpv_bf | WcombT | qw (57.8 MB full)
// ---------------------------------------------------------------------------
extern "C" void kernel_launch(void* const* d_in, const int* in_sizes, int n_in,
                              void* d_out, int out_size, void* d_ws, size_t ws_size,
                              hipStream_t stream) {
  const float* xq    = (const float*)d_in[0];
  const float* xk    = (const float*)d_in[1];
  const float* Wq    = (const float*)d_in[2];
  const float* Wkv   = (const float*)d_in[3];
  const float* Wpq   = (const float*)d_in[4];
  const float* Wpkv  = (const float*)d_in[5];
  const float* Wproj = (const float*)d_in[6];
  const float* bproj = (const float*)d_in[7];

  float* out   = (float*)d_out;
  float* attn2 = out + (size_t)MTOT*DIM;

  ushort* ws     = (ushort*)d_ws;
  ushort* xbf    = ws;
  ushort* kvbf   = xbf + (size_t)MTOT*FR*DIM;
  ushort* qbf    = kvbf + (size_t)MTOT*2*DIM;
  ushort* xqbf   = qbf + (size_t)MTOT*DIM;
  ushort* xkbf   = xqbf + (size_t)MTOT*DIM;
  ushort* Vt     = xqbf;                        // alias (dead post-proj)
  ushort* xa     = xkbf;                        // alias (dead post-proj)
  ushort* WqT    = xkbf + (size_t)MTOT*DIM;
  ushort* WkvT   = WqT  + (size_t)DIM*DIM;
  ushort* WpqT   = WkvT + (size_t)2*DIM*DIM;
  ushort* WprT   = WpqT + (size_t)DIM*DIM;
  ushort* Wpk_bf = WprT + (size_t)DIM*DIM;
  ushort* Wpv_bf = Wpk_bf + (size_t)DIM*DIM;
  ushort* WcombT = Wpv_bf + (size_t)DIM*DIM;
  ushort* qw     = WcombT + (size_t)DIM*DIM;    // [3136][12][768] bf16, 57.8 MB

  dim3 blk(256);
  const int n4 = MTOT*DIM/4;

  cvt_all<<<dim3(4704 + 1152 + 1152), blk, 0, stream>>>(
      xq, xk, xqbf, xkbf, Wq, Wkv, Wpq, Wproj, Wpkv,
      WqT, WkvT, WpqT, WprT, Wpk_bf, Wpv_bf, n4);

  // WcombT[n][k] = sum_m Wproj[m][n]*Wpv[k][m]  (fused z+out projection)
  gemm128<false,true><<<dim3(6, 6), blk, 0, stream>>>(
      WprT, Wpv_bf, WcombT, nullptr, DIM, DIM, 1.0f);

  proj_pair<<<dim3(18, (MTOT+127)/128), blk, 0, stream>>>(
      xqbf, xkbf, WqT, WkvT, qbf, kvbf);
  vtrans<<<dim3(BDIM*FR*NH), blk, 0, stream>>>(kvbf, Vt);
  stage1_mfma<<<dim3(BDIM*NH, FR, (SEQ+127)/128), blk, 0, stream>>>(qbf, kvbf, Vt, xbf);

  // fused q2 + qw (replaces q2 gemm + qwgemm; no q2bf round-trip)
  q2qw<<<dim3(12, 25), blk, 0, stream>>>(xbf, WpqT, Wpk_bf, qw);

  logits_sa<<<dim3(MTOT/4), blk, 0, stream>>>(qw, xbf, attn2, xa);

  // out = xa @ Wcomb + bproj  (z-GEMM fused away)
  gemm128<true,false><<<dim3(6, (MTOT+127)/128), blk, 0, stream>>>(
      xa, WcombT, out, bproj, MTOT, DIM, 1.0f);
}

// Round 10
// 241.579 us; speedup vs baseline: 1.0459x; 1.0459x over previous
//
#include <hip/hip_runtime.h>

#define BDIM 2
#define SEQ  1568
#define DIM  768
#define NH   12
#define FR   8
#define NTOK 196
#define HD   64
#define MTOT (BDIM*SEQ)   // 3136 token rows
#define M2   (MTOT*FR)    // 25088 (t,f) rows

typedef __attribute__((ext_vector_type(8))) short s16x8;
typedef __attribute__((ext_vector_type(4))) float f32x4;
typedef __attribute__((ext_vector_type(16))) float f32x16;
typedef __attribute__((ext_vector_type(4))) int i32x4;

static __device__ __forceinline__ float bf2f(ushort u) {
  return __uint_as_float(((unsigned)u) << 16);
}
static __device__ __forceinline__ ushort f2bf(float f) {
  unsigned u = __float_as_uint(f);
  unsigned r = (u + 0x7fffu + ((u >> 16) & 1u)) >> 16;
  return (ushort)r;
}
static __device__ __forceinline__ f32x4 mfma16(s16x8 a, s16x8 b, f32x4 c) {
  return __builtin_amdgcn_mfma_f32_16x16x32_bf16(a, b, c, 0, 0, 0);
}
static __device__ __forceinline__ f32x16 mfma32(s16x8 a, s16x8 b, f32x16 c) {
  return __builtin_amdgcn_mfma_f32_32x32x16_bf16(a, b, c, 0, 0, 0);
}
static __device__ __forceinline__ int cvtpk(float lo, float hi) {
  int r;
  asm("v_cvt_pk_bf16_f32 %0, %1, %2" : "=v"(r) : "v"(lo), "v"(hi));
  return r;
}
static __device__ __forceinline__ void gload_lds16(const ushort* g, ushort* l) {
  __builtin_amdgcn_global_load_lds(
      (const __attribute__((address_space(1))) void*)g,
      (__attribute__((address_space(3))) void*)l, 16, 0, 0);
}

// ---------------------------------------------------------------------------
// Fused convert: inputs -> bf16, 4 weights transposed -> bf16, and straight
// bf16 copies of the Wpkv halves (Wpk_bf, Wpv_bf) for the qw / Wcomb paths.
// grid: 4704 input + 1152 transpose (nx24 x ky12 x wid4) + 1152 straight.
// ---------------------------------------------------------------------------
__global__ __launch_bounds__(256)
void cvt_all(const float* __restrict__ xq, const float* __restrict__ xk,
             ushort* __restrict__ xqbf, ushort* __restrict__ xkbf,
             const float* __restrict__ Wq, const float* __restrict__ Wkv,
             const float* __restrict__ Wpq, const float* __restrict__ Wproj,
             const float* __restrict__ Wpkv,
             ushort* __restrict__ WqT, ushort* __restrict__ WkvT,
             ushort* __restrict__ WpqT, ushort* __restrict__ WprT,
             ushort* __restrict__ Wpk_bf, ushort* __restrict__ Wpv_bf,
             int n4) {
  __shared__ float T[64][65];
  const int blk = blockIdx.x;
  const int tid = threadIdx.x;

  if (blk < 4704) {             // input conversion
    int i = blk*256 + tid;
    const float* src; ushort* dst; int j;
    if (i < n4)        { src = xq; dst = xqbf; j = i; }
    else               { src = xk; dst = xkbf; j = i - n4; }
    float4 v = ((const float4*)src)[j];
    ushort4 o; o.x = f2bf(v.x); o.y = f2bf(v.y); o.z = f2bf(v.z); o.w = f2bf(v.w);
    ((ushort4*)dst)[j] = o;
    return;
  }

  if (blk < 5856) {             // weight transpose (4 weights)
    int idx = blk - 4704;
    const int wid = idx / 288; idx %= 288;
    const int ky = idx / 24;
    const int nx = idx % 24;
    const float* W; ushort* WT; int N;
    switch (wid) {
      case 0: W = Wq;    WT = WqT;   N = DIM;   break;
      case 1: W = Wkv;   WT = WkvT;  N = 2*DIM; break;
      case 2: W = Wpq;   WT = WpqT;  N = DIM;   break;
      default: W = Wproj; WT = WprT; N = DIM;   break;
    }
    if (nx >= N/64) return;
    #pragma unroll
    for (int it = 0; it < 4; it++) {
      int id2 = it*256 + tid;
      int r = id2 >> 4, c4 = (id2 & 15) << 2;
      float4 v = *(const float4*)&W[(size_t)(ky*64 + r)*N + nx*64 + c4];
      T[r][c4+0] = v.x; T[r][c4+1] = v.y; T[r][c4+2] = v.z; T[r][c4+3] = v.w;
    }
    __syncthreads();
    #pragma unroll
    for (int it = 0; it < 4; it++) {
      int id2 = it*256 + tid;
      int n = id2 >> 4, k4 = (id2 & 15) << 2;
      ushort4 o;
      o.x = f2bf(T[k4+0][n]); o.y = f2bf(T[k4+1][n]);
      o.z = f2bf(T[k4+2][n]); o.w = f2bf(T[k4+3][n]);
      *(ushort4*)&WT[(size_t)(nx*64 + n)*DIM + ky*64 + k4] = o;
    }
    return;
  }

  // straight bf16 copies of Wpkv halves: Wpk_bf / Wpv_bf [768][768]
  {
    int id2 = blk - 5856;            // 0..1151
    int half = id2 / 576;
    int e = (id2 % 576)*256 + tid;   // float4 index within 768x768
    int r = e / 192;
    int c4 = (e % 192) * 4;
    float4 v = *(const float4*)&Wpkv[(size_t)r*(2*DIM) + half*DIM + c4];
    ushort4 o; o.x = f2bf(v.x); o.y = f2bf(v.y); o.z = f2bf(v.z); o.w = f2bf(v.w);
    ushort* dst = half ? Wpv_bf : Wpk_bf;
    *(ushort4*)&dst[(size_t)r*DIM + c4] = o;
  }
}

// Vt[(b,f,h)][64][224] bf16, zero-padded n>=196. grid = 192
__global__ __launch_bounds__(256)
void vtrans(const ushort* __restrict__ kvbf, ushort* __restrict__ Vt) {
  __shared__ ushort Vl[NTOK][72];
  const int x = blockIdx.x;
  const int h = x % NH, f = (x / NH) % FR, b = x / (NH*FR);
  const int tid = threadIdx.x;
  for (int idx = tid; idx < NTOK*16; idx += 256) {
    int n = idx >> 4, c4 = (idx & 15) << 2;
    const ushort* p = kvbf + (size_t)(b*SEQ + f*NTOK + n)*(2*DIM) + DIM + h*HD + c4;
    *(ushort4*)&Vl[n][c4] = *(const ushort4*)p;
  }
  __syncthreads();
  ushort* vb = Vt + (size_t)x * (HD*224);
  for (int idx = tid; idx < 64*56; idx += 256) {
    int d = idx / 56, n4 = (idx % 56) << 2;
    ushort4 o;
    o.x = (n4+0 < NTOK) ? Vl[n4+0][d] : (ushort)0;
    o.y = (n4+1 < NTOK) ? Vl[n4+1][d] : (ushort)0;
    o.z = (n4+2 < NTOK) ? Vl[n4+2][d] : (ushort)0;
    o.w = (n4+3 < NTOK) ? Vl[n4+3][d] : (ushort)0;
    *(ushort4*)&vb[(size_t)d*224 + n4] = o;
  }
}

// ---------------------------------------------------------------------------
// Merged q+kv projection, 128x128 tiles. grid (18, 25) = 450 blocks >= CU
// count, so the wider tile's better MFMA/staging ratio applies without the
// device-fill penalty seen on the 150-block out-GEMM (R9 lesson).
// bx<6: qbf = 0.125*(xq@Wq) cols bx*128; else kvbf = xk@Wkv cols (bx-6)*128.
// ---------------------------------------------------------------------------
__global__ __launch_bounds__(256)
void proj_pair(const ushort* __restrict__ xqbf, const ushort* __restrict__ xkbf,
               const ushort* __restrict__ WqT, const ushort* __restrict__ WkvT,
               ushort* __restrict__ qbf, ushort* __restrict__ kvbf)
{
  __shared__ ushort As[128][32];
  __shared__ ushort Bs[128][32];
  const int bx = blockIdx.x, by = blockIdx.y;
  const ushort* A; const ushort* Bt; ushort* C; int N, col0; float scale;
  if (bx < 6) { A = xqbf; Bt = WqT;  C = qbf;  N = DIM;   col0 = bx*128;     scale = 0.125f; }
  else        { A = xkbf; Bt = WkvT; C = kvbf; N = 2*DIM; col0 = (bx-6)*128; scale = 1.0f; }

  const int tid = threadIdx.x;
  const int w = tid >> 6, lane = tid & 63;
  const int lq = lane & 15, quad = lane >> 4;
  const int wr = (w >> 1) * 64, wc = (w & 1) * 64;
  const int lrow = tid >> 2, lcol = (tid & 3) << 3;

  int ar0 = by*128 + lrow;       if (ar0 > MTOT-1) ar0 = MTOT-1;
  int ar1 = by*128 + 64 + lrow;  if (ar1 > MTOT-1) ar1 = MTOT-1;
  const size_t aoff0 = (size_t)ar0*DIM + lcol;
  const size_t aoff1 = (size_t)ar1*DIM + lcol;
  const size_t boff0 = (size_t)(col0 + lrow)*DIM + lcol;
  const size_t boff1 = (size_t)(col0 + 64 + lrow)*DIM + lcol;

  f32x4 acc[4][4] = {};
  for (int k0 = 0; k0 < DIM; k0 += 32) {
    __syncthreads();
    gload_lds16(A  + aoff0 + k0, &As[w*16][0]);
    gload_lds16(A  + aoff1 + k0, &As[64 + w*16][0]);
    gload_lds16(Bt + boff0 + k0, &Bs[w*16][0]);
    gload_lds16(Bt + boff1 + k0, &Bs[64 + w*16][0]);
    __syncthreads();
    s16x8 af[4], bw[4];
    #pragma unroll
    for (int i = 0; i < 4; i++) af[i] = *(const s16x8*)&As[wr + i*16 + lq][quad*8];
    #pragma unroll
    for (int j = 0; j < 4; j++) bw[j] = *(const s16x8*)&Bs[wc + j*16 + lq][quad*8];
    #pragma unroll
    for (int i = 0; i < 4; i++)
      #pragma unroll
      for (int j = 0; j < 4; j++)
        acc[i][j] = mfma16(af[i], bw[j], acc[i][j]);
  }

  #pragma unroll
  for (int i = 0; i < 4; i++) {
    #pragma unroll
    for (int r = 0; r < 4; r++) {
      int row = by*128 + wr + i*16 + quad*4 + r;
      if (row < MTOT) {
        #pragma unroll
        for (int j = 0; j < 4; j++)
          C[(size_t)row*N + col0 + wc + j*16 + lq] = f2bf(acc[i][j][r] * scale);
      }
    }
  }
}

// ---------------------------------------------------------------------------
// 128x64-tile GEMM (R8-proven). grid (N/64, ceil(M/128)). K=768.
// 300 blocks for the M=3136 out-proj: keeps grid >= CU count (R9 lesson:
// 128x128 would give 150 blocks < 256 CUs -> device underfill).
// BF16OUT: C is ushort bf16; else float.
// ---------------------------------------------------------------------------
template<bool BIAS, bool BF16OUT>
__global__ __launch_bounds__(256)
void gemm64(const ushort* __restrict__ A, const ushort* __restrict__ Bt,
            void* __restrict__ Cv, const float* __restrict__ bias,
            int M, int N, float scale)
{
  __shared__ ushort As[128][32];
  __shared__ ushort Bs[64][32];
  const int bx = blockIdx.x, by = blockIdx.y;
  const int tid = threadIdx.x;
  const int w = tid >> 6, lane = tid & 63;
  const int lq = lane & 15, quad = lane >> 4;
  const int lrow = tid >> 2, lcol = (tid & 3) << 3;
  const int col0 = bx*64;

  int ar0 = by*128 + lrow;       if (ar0 > M-1) ar0 = M-1;
  int ar1 = by*128 + 64 + lrow;  if (ar1 > M-1) ar1 = M-1;
  const size_t aoff0 = (size_t)ar0*DIM + lcol;
  const size_t aoff1 = (size_t)ar1*DIM + lcol;
  const size_t boff = (size_t)(col0 + lrow)*DIM + lcol;

  f32x4 acc[2][4] = {};
  for (int k0 = 0; k0 < DIM; k0 += 32) {
    __syncthreads();
    gload_lds16(A  + aoff0 + k0, &As[w*16][0]);
    gload_lds16(A  + aoff1 + k0, &As[64 + w*16][0]);
    gload_lds16(Bt + boff  + k0, &Bs[w*16][0]);
    __syncthreads();
    s16x8 af[2], bw[4];
    #pragma unroll
    for (int i = 0; i < 2; i++) af[i] = *(const s16x8*)&As[w*32 + i*16 + lq][quad*8];
    #pragma unroll
    for (int j = 0; j < 4; j++) bw[j] = *(const s16x8*)&Bs[j*16 + lq][quad*8];
    #pragma unroll
    for (int i = 0; i < 2; i++)
      #pragma unroll
      for (int j = 0; j < 4; j++)
        acc[i][j] = mfma16(af[i], bw[j], acc[i][j]);
  }

  #pragma unroll
  for (int i = 0; i < 2; i++) {
    #pragma unroll
    for (int r = 0; r < 4; r++) {
      int row = by*128 + w*32 + i*16 + quad*4 + r;
      if (row < M) {
        #pragma unroll
        for (int j = 0; j < 4; j++) {
          int col = col0 + j*16 + lq;
          float v = acc[i][j][r] * scale;
          if (BIAS) v += bias[col];
          if (BF16OUT) ((ushort*)Cv)[(size_t)row*N + col] = f2bf(v);
          else         ((float*)Cv)[(size_t)row*N + col] = v;
        }
      }
    }
  }
}

// ---------------------------------------------------------------------------
// FUSED q2 + qw kernel. grid (12 = head, 25 Mtiles).
// Phase 1: q2 tile = 0.125*(x_diag @ Wpq) cols h*64..+63  (K=768, DIAG gather)
//          -> parked in LDS q2s[128][72] bf16 (same-wave rows only).
// Phase 2: qw[row][h][c] = sum_dd q2[row][dd]*Wpk[c][h*64+dd] for c in 12
//          64-wide tiles (K=64, Bs restaged per 32-chunk, 1 gload/step).
// ---------------------------------------------------------------------------
__global__ __launch_bounds__(256)
void q2qw(const ushort* __restrict__ x, const ushort* __restrict__ WpqT,
          const ushort* __restrict__ Wpk, ushort* __restrict__ qw)
{
  __shared__ ushort As[128][32];
  __shared__ ushort Bs[64][32];
  __shared__ ushort q2s[128][72];
  const int h = blockIdx.x, by = blockIdx.y;
  const int tid = threadIdx.x;
  const int w = tid >> 6, lane = tid & 63;
  const int lq = lane & 15, quad = lane >> 4;
  const int lrow = tid >> 2, lcol = (tid & 3) << 3;

  int ar0 = by*128 + lrow;       if (ar0 > MTOT-1) ar0 = MTOT-1;
  int ar1 = by*128 + 64 + lrow;  if (ar1 > MTOT-1) ar1 = MTOT-1;
  const int f0 = (ar0 % SEQ) / NTOK, f1 = (ar1 % SEQ) / NTOK;
  const size_t aoff0 = ((size_t)ar0*FR + f0)*DIM + lcol;
  const size_t aoff1 = ((size_t)ar1*FR + f1)*DIM + lcol;
  const size_t boff  = (size_t)(h*64 + lrow)*DIM + lcol;

  // ---- phase 1: q2 tile (DIAG A-gather, K=768)
  f32x4 acc[2][4] = {};
  for (int k0 = 0; k0 < DIM; k0 += 32) {
    __syncthreads();
    gload_lds16(x    + aoff0 + k0, &As[w*16][0]);
    gload_lds16(x    + aoff1 + k0, &As[64 + w*16][0]);
    gload_lds16(WpqT + boff  + k0, &Bs[w*16][0]);
    __syncthreads();
    s16x8 af[2], bw[4];
    #pragma unroll
    for (int i = 0; i < 2; i++) af[i] = *(const s16x8*)&As[w*32 + i*16 + lq][quad*8];
    #pragma unroll
    for (int j = 0; j < 4; j++) bw[j] = *(const s16x8*)&Bs[j*16 + lq][quad*8];
    #pragma unroll
    for (int i = 0; i < 2; i++)
      #pragma unroll
      for (int j = 0; j < 4; j++)
        acc[i][j] = mfma16(af[i], bw[j], acc[i][j]);
  }

  // ---- park q2 tile in LDS bf16 (scale 0.125); rows are wave-local
  #pragma unroll
  for (int i = 0; i < 2; i++)
    #pragma unroll
    for (int r = 0; r < 4; r++) {
      int row = w*32 + i*16 + quad*4 + r;
      #pragma unroll
      for (int j = 0; j < 4; j++)
        q2s[row][j*16 + lq] = f2bf(acc[i][j][r] * 0.125f);
    }

  // ---- phase 2: qw tiles over c (12 x 64 cols), K=64 from q2s
  for (int ct = 0; ct < 12; ++ct) {
    f32x4 acc2[2][4] = {};
    #pragma unroll
    for (int k0 = 0; k0 < 64; k0 += 32) {
      __syncthreads();
      gload_lds16(Wpk + (size_t)(ct*64 + lrow)*DIM + h*HD + k0 + lcol, &Bs[w*16][0]);
      __syncthreads();
      s16x8 af[2], bw[4];
      #pragma unroll
      for (int i = 0; i < 2; i++)
        af[i] = *(const s16x8*)&q2s[w*32 + i*16 + lq][k0 + quad*8];
      #pragma unroll
      for (int j = 0; j < 4; j++) bw[j] = *(const s16x8*)&Bs[j*16 + lq][quad*8];
      #pragma unroll
      for (int i = 0; i < 2; i++)
        #pragma unroll
        for (int j = 0; j < 4; j++)
          acc2[i][j] = mfma16(af[i], bw[j], acc2[i][j]);
    }
    #pragma unroll
    for (int i = 0; i < 2; i++) {
      #pragma unroll
      for (int r = 0; r < 4; r++) {
        int row = by*128 + w*32 + i*16 + quad*4 + r;
        if (row < MTOT) {
          #pragma unroll
          for (int j = 0; j < 4; j++)
            qw[(size_t)row*(NH*DIM) + h*DIM + ct*64 + j*16 + lq] = f2bf(acc2[i][j][r]);
        }
      }
    }
  }
}

// ---------------------------------------------------------------------------
// Fused logits + softmax + x-aggregation. grid 784 (4 t / block, 1 t / wave).
// Stages x[4][8][768] and qw[4][12][768] in LDS (264-elem chunks: bank-step
// 12 -> conflict-free A, 2-way B = free). Per wave: 24 MFMA k-steps give
// logits[f=quad*4+r][h=lq]; in-wave softmax over f (one shfl_xor 16);
// writes attn2 and computes xa from the x STILL IN LDS (no global re-read).
// ---------------------------------------------------------------------------
__global__ __launch_bounds__(256)
void logits_sa(const ushort* __restrict__ qw, const ushort* __restrict__ x,
               float* __restrict__ attn2, ushort* __restrict__ xa)
{
  __shared__ ushort xs[4*8*792];    // 49.5 KB  [tf][ch*264+cc]
  __shared__ ushort qws[4*12*792];  // 74.25 KB [th][ch*264+cc]
  __shared__ float  a_s[4][NH][FR]; // 1.5 KB
  const int tid = threadIdx.x;
  const int t0 = blockIdx.x * 4;

  #pragma unroll
  for (int r = 0; r < 12; ++r) {    // stage x: 4t*8f*96 vec8
    int id = r*256 + tid;
    int tf = id / 96, v8 = id % 96;
    int ch = v8 >> 5, cc = v8 & 31;
    s16x8 v = *(const s16x8*)(x + ((size_t)(t0 + (tf >> 3))*FR + (tf & 7))*DIM + v8*8);
    *(s16x8*)&xs[tf*792 + ch*264 + cc*8] = v;
  }
  #pragma unroll
  for (int r = 0; r < 18; ++r) {    // stage qw: 4t*12h*96 vec8
    int id = r*256 + tid;
    int th = id / 96, v8 = id % 96;
    int ch = v8 >> 5, cc = v8 & 31;
    s16x8 v = *(const s16x8*)(qw + (size_t)(t0 + th/12)*(NH*DIM) + (th%12)*DIM + v8*8);
    *(s16x8*)&qws[th*792 + ch*264 + cc*8] = v;
  }
  __syncthreads();

  const int w = tid >> 6, lane = tid & 63;
  const int lq = lane & 15, quad = lane >> 4;
  const int fr = lq & 7;                      // A row (rows 8-15 duplicate f)
  const int hc = (lq < 12) ? lq : 0;          // B col clamp
  f32x4 acc = {};
  #pragma unroll
  for (int ks = 0; ks < 24; ++ks) {
    int ch = ks >> 3, cc = (ks & 7) * 32;
    s16x8 a = *(const s16x8*)&xs[(w*8 + fr)*792 + ch*264 + cc + quad*8];
    s16x8 b = *(const s16x8*)&qws[(w*12 + hc)*792 + ch*264 + cc + quad*8];
    acc = mfma16(a, b, acc);
  }

  // softmax over f: own 4 f's (rows quad*4+r, quad<2) + partner via xor 16
  float m4 = fmaxf(fmaxf(acc[0], acc[1]), fmaxf(acc[2], acc[3]));
  float M = fmaxf(m4, __shfl_xor(m4, 16));
  float e0 = __expf(acc[0]-M), e1 = __expf(acc[1]-M);
  float e2 = __expf(acc[2]-M), e3 = __expf(acc[3]-M);
  float s4 = (e0+e1)+(e2+e3);
  float S = s4 + __shfl_xor(s4, 16);
  float inv = 1.0f / S;
  if (quad < 2 && lq < 12) {
    int gt = t0 + w;
    int b = gt / SEQ, sI = gt % SEQ;
    float4 av; av.x = e0*inv; av.y = e1*inv; av.z = e2*inv; av.w = e3*inv;
    *(float4*)(attn2 + ((size_t)(b*NH + hc)*SEQ + sI)*FR + quad*4) = av;
    a_s[w][hc][quad*4+0] = av.x; a_s[w][hc][quad*4+1] = av.y;
    a_s[w][hc][quad*4+2] = av.z; a_s[w][hc][quad*4+3] = av.w;
  }
  __syncthreads();

  // xa[t,c] = sum_f a_s[t][h(c)][f] * x[t,f,c]; x read from LDS
  #pragma unroll
  for (int it = 0; it < 2; ++it) {
    int id = it*256 + tid;
    if (id < 384) {
      int tt = id / 96, v8 = id % 96;
      int ch = v8 >> 5, cc = v8 & 31;
      int h = v8 >> 3;
      float av[8] = {};
      #pragma unroll
      for (int f = 0; f < FR; ++f) {
        float a = a_s[tt][h][f];
        s16x8 xv = *(const s16x8*)&xs[(tt*8 + f)*792 + ch*264 + cc*8];
        #pragma unroll
        for (int e = 0; e < 8; ++e) av[e] += a * bf2f((ushort)xv[e]);
      }
      ushort4 o0, o1;
      o0.x = f2bf(av[0]); o0.y = f2bf(av[1]); o0.z = f2bf(av[2]); o0.w = f2bf(av[3]);
      o1.x = f2bf(av[4]); o1.y = f2bf(av[5]); o1.z = f2bf(av[6]); o1.w = f2bf(av[7]);
      ushort* op = xa + (size_t)(t0 + tt)*DIM + v8*8;
      *(ushort4*)op = o0; *(ushort4*)(op + 4) = o1;
    }
  }
}

// ---------------------------------------------------------------------------
// Stage 1, 32x32 MFMA, swapped operands (S^T = K.Q^T), in-register P.
// (unchanged from R2-verified version)
// ---------------------------------------------------------------------------
__global__ __launch_bounds__(256)
void stage1_mfma(const ushort* __restrict__ qbf, const ushort* __restrict__ kvbf,
                 const ushort* __restrict__ Vt, ushort* __restrict__ x)
{
  __shared__ ushort sh[208*64];   // 26624 B: K tile, then per-wave X transpose

  const int bh = blockIdx.x;   // 0..23
  const int f  = blockIdx.y;   // 0..7
  const int qt = blockIdx.z;   // 0..12
  const int b = bh / NH, h = bh % NH;
  const int tid = threadIdx.x;
  const int w = tid >> 6, lane = tid & 63;
  const int l31 = lane & 31, hl = lane >> 5;

  const ushort* kbase = kvbf + ((size_t)b*SEQ + f*NTOK)*(2*DIM) + h*HD;
  #pragma unroll
  for (int p = 0; p < 6; ++p) {
    const int c = w*6 + p;                         // 8-row chunk, rows < 192
    const int row = c*8 + (lane >> 3);
    const ushort* src = kbase + (size_t)row*(2*DIM)
                      + (((lane & 7) ^ (lane >> 3)) << 3);
    gload_lds16(src, &sh[c*512]);
  }
  { // rows 192..207: 192..195 from global, 196..207 zero (same swizzle)
    const int row = 192 + (tid >> 4);
    const int c4  = (tid & 15) << 2;
    ushort4 v; v.x = 0; v.y = 0; v.z = 0; v.w = 0;
    if (row < NTOK)
      v = *(const ushort4*)(kbase + (size_t)row*(2*DIM) + c4);
    *(ushort4*)&sh[row*64 + ((((c4 >> 3) ^ (row & 7)) << 3) | (c4 & 7))] = v;
  }

  int qrow = qt*128 + w*32 + l31; if (qrow > SEQ-1) qrow = SEQ-1;
  const ushort* qp = qbf + ((size_t)b*SEQ + qrow)*DIM + h*HD + hl*8;
  const s16x8 bq0 = *(const s16x8*)(qp);
  const s16x8 bq1 = *(const s16x8*)(qp + 16);
  const s16x8 bq2 = *(const s16x8*)(qp + 32);
  const s16x8 bq3 = *(const s16x8*)(qp + 48);

  __syncthreads();

  f32x16 acc[7];
  {
    f32x16 z = {};
    #pragma unroll
    for (int nt = 0; nt < 7; ++nt) acc[nt] = z;
  }
  const int sx = l31 & 7;
  #pragma unroll
  for (int nt = 0; nt < 7; ++nt) {
    const int rl = (nt == 6) ? (l31 & 15) : l31;   // keep tile-6 A-reads in bounds
    const int rbase = (nt*32 + rl)*64;
    acc[nt] = mfma32(*(const s16x8*)&sh[rbase + (((0 + hl) ^ sx) << 3)], bq0, acc[nt]);
    acc[nt] = mfma32(*(const s16x8*)&sh[rbase + (((2 + hl) ^ sx) << 3)], bq1, acc[nt]);
    acc[nt] = mfma32(*(const s16x8*)&sh[rbase + (((4 + hl) ^ sx) << 3)], bq2, acc[nt]);
    acc[nt] = mfma32(*(const s16x8*)&sh[rbase + (((6 + hl) ^ sx) << 3)], bq3, acc[nt]);
  }

  __syncthreads();   // all K reads done -> sh reusable for X transpose

  float s0 = 0.f, s1 = 0.f, s2 = 0.f, s3 = 0.f;
  #pragma unroll
  for (int nt = 0; nt < 7; ++nt) {
    #pragma unroll
    for (int g = 0; g < 16; ++g) {
      float e;
      if (nt == 6) {
        if (g < 4) { e = __expf(acc[6][g]); if (hl) e = 0.f; }  // n=192..195 only
        else e = 0.f;
      } else {
        e = __expf(acc[nt][g]);
      }
      acc[nt][g] = e;
      if ((g & 3) == 0) s0 += e; else if ((g & 3) == 1) s1 += e;
      else if ((g & 3) == 2) s2 += e; else s3 += e;
    }
  }
  float sum = (s0 + s1) + (s2 + s3);
  sum += __shfl_xor(sum, 32);
  const float sinv = 1.0f / sum;

  f32x16 o0, o1;
  { f32x16 z = {}; o0 = z; o1 = z; }
  const ushort* vb = Vt + ((size_t)((b*FR + f)*NH + h)) * (HD*224);
  const ushort* vr0 = vb + (size_t)l31*224 + hl*8;
  const ushort* vr1 = vr0 + 32*224;
  #pragma unroll
  for (int nt = 0; nt < 7; ++nt) {
    #pragma unroll
    for (int kh = 0; kh < 2; ++kh) {
      int w0 = cvtpk(acc[nt][8*kh+0], acc[nt][8*kh+1]);
      int w1 = cvtpk(acc[nt][8*kh+2], acc[nt][8*kh+3]);
      int w2 = cvtpk(acc[nt][8*kh+4], acc[nt][8*kh+5]);
      int w3 = cvtpk(acc[nt][8*kh+6], acc[nt][8*kh+7]);
      asm("v_permlane32_swap_b32 %0, %1" : "+v"(w0), "+v"(w2));
      asm("v_permlane32_swap_b32 %0, %1" : "+v"(w1), "+v"(w3));
      union { i32x4 i; s16x8 s; } u;
      u.i.x = w0; u.i.y = w1; u.i.z = w2; u.i.w = w3;
      const int ks = nt*2 + kh;
      const s16x8 va0 = *(const s16x8*)(vr0 + ks*16);
      const s16x8 va1 = *(const s16x8*)(vr1 + ks*16);
      o0 = mfma32(va0, u.s, o0);
      o1 = mfma32(va1, u.s, o1);
    }
  }

  ushort* XT = sh + w*2048;
  #pragma unroll
  for (int dt = 0; dt < 2; ++dt) {
    #pragma unroll
    for (int c = 0; c < 4; ++c) {
      #pragma unroll
      for (int rp = 0; rp < 2; ++rp) {
        const float lo = (dt ? o1[4*c + 2*rp]     : o0[4*c + 2*rp])     * sinv;
        const float hi = (dt ? o1[4*c + 2*rp + 1] : o0[4*c + 2*rp + 1]) * sinv;
        const int word = cvtpk(lo, hi);
        const int d = dt*32 + 8*c + 4*hl + 2*rp;
        *(uint*)&XT[l31*64 + (((d >> 3) ^ (l31 & 7)) << 3) + (d & 7)] = (uint)word;
      }
    }
  }
  #pragma unroll
  for (int it = 0; it < 4; ++it) {
    const int q = it*8 + (lane >> 3);
    const int g = lane & 7;
    s16x8 xv = *(const s16x8*)&XT[q*64 + ((g ^ (q & 7)) << 3)];
    const int s = qt*128 + w*32 + q;
    if (s < SEQ) {
      ushort* xp = x + (((size_t)b*SEQ + s)*FR + f)*DIM + h*HD + g*8;
      *(s16x8*)xp = xv;
    }
  }
}

// ---------------------------------------------------------------------------
// Workspace (ushort units; ~123 MB used; harness memsets ~268 MB of ws):
//  xbf | kvbf | qbf | xqbf (Vt alias) | xkbf (xa alias) |
//  WqT | WkvT | WpqT | WprT | Wpk_bf | Wpv_bf | WcombT | qw (57.8 MB full)
// ---------------------------------------------------------------------------
extern "C" void kernel_launch(void* const* d_in, const int* in_sizes, int n_in,
                              void* d_out, int out_size, void* d_ws, size_t ws_size,
                              hipStream_t stream) {
  const float* xq    = (const float*)d_in[0];
  const float* xk    = (const float*)d_in[1];
  const float* Wq    = (const float*)d_in[2];
  const float* Wkv   = (const float*)d_in[3];
  const float* Wpq   = (const float*)d_in[4];
  const float* Wpkv  = (const float*)d_in[5];
  const float* Wproj = (const float*)d_in[6];
  const float* bproj = (const float*)d_in[7];

  float* out   = (float*)d_out;
  float* attn2 = out + (size_t)MTOT*DIM;

  ushort* ws     = (ushort*)d_ws;
  ushort* xbf    = ws;
  ushort* kvbf   = xbf + (size_t)MTOT*FR*DIM;
  ushort* qbf    = kvbf + (size_t)MTOT*2*DIM;
  ushort* xqbf   = qbf + (size_t)MTOT*DIM;
  ushort* xkbf   = xqbf + (size_t)MTOT*DIM;
  ushort* Vt     = xqbf;                        // alias (dead post-proj)
  ushort* xa     = xkbf;                        // alias (dead post-proj)
  ushort* WqT    = xkbf + (size_t)MTOT*DIM;
  ushort* WkvT   = WqT  + (size_t)DIM*DIM;
  ushort* WpqT   = WkvT + (size_t)2*DIM*DIM;
  ushort* WprT   = WpqT + (size_t)DIM*DIM;
  ushort* Wpk_bf = WprT + (size_t)DIM*DIM;
  ushort* Wpv_bf = Wpk_bf + (size_t)DIM*DIM;
  ushort* WcombT = Wpv_bf + (size_t)DIM*DIM;
  ushort* qw     = WcombT + (size_t)DIM*DIM;    // [3136][12][768] bf16, 57.8 MB

  dim3 blk(256);
  const int n4 = MTOT*DIM/4;

  cvt_all<<<dim3(4704 + 1152 + 1152), blk, 0, stream>>>(
      xq, xk, xqbf, xkbf, Wq, Wkv, Wpq, Wproj, Wpkv,
      WqT, WkvT, WpqT, WprT, Wpk_bf, Wpv_bf, n4);

  // WcombT[n][k] = sum_m Wproj[m][n]*Wpv[k][m]  (fused z+out projection)
  gemm64<false,true><<<dim3(12, 6), blk, 0, stream>>>(
      WprT, Wpv_bf, WcombT, nullptr, DIM, DIM, 1.0f);

  proj_pair<<<dim3(18, (MTOT+127)/128), blk, 0, stream>>>(
      xqbf, xkbf, WqT, WkvT, qbf, kvbf);
  vtrans<<<dim3(BDIM*FR*NH), blk, 0, stream>>>(kvbf, Vt);
  stage1_mfma<<<dim3(BDIM*NH, FR, (SEQ+127)/128), blk, 0, stream>>>(qbf, kvbf, Vt, xbf);

  // fused q2 + qw (replaces q2 gemm + qwgemm; no q2bf round-trip)
  q2qw<<<dim3(12, 25), blk, 0, stream>>>(xbf, WpqT, Wpk_bf, qw);

  logits_sa<<<dim3(MTOT/4), blk, 0, stream>>>(qw, xbf, attn2, xa);

  // out = xa @ Wcomb + bproj  (z-GEMM fused away; 128x64 tiles -> 300 blocks)
  gemm64<true,false><<<dim3(12, (MTOT+127)/128), blk, 0, stream>>>(
      xa, WcombT, out, bproj, MTOT, DIM, 1.0f);
}

// Round 11
// 236.942 us; speedup vs baseline: 1.0664x; 1.0196x over previous
//
#include <hip/hip_runtime.h>

#define BDIM 2
#define SEQ  1568
#define DIM  768
#define NH   12
#define FR   8
#define NTOK 196
#define HD   64
#define MTOT (BDIM*SEQ)   // 3136 token rows
#define M2   (MTOT*FR)    // 25088 (t,f) rows

typedef __attribute__((ext_vector_type(8))) short s16x8;
typedef __attribute__((ext_vector_type(4))) float f32x4;
typedef __attribute__((ext_vector_type(16))) float f32x16;
typedef __attribute__((ext_vector_type(4))) int i32x4;

static __device__ __forceinline__ float bf2f(ushort u) {
  return __uint_as_float(((unsigned)u) << 16);
}
static __device__ __forceinline__ ushort f2bf(float f) {
  unsigned u = __float_as_uint(f);
  unsigned r = (u + 0x7fffu + ((u >> 16) & 1u)) >> 16;
  return (ushort)r;
}
static __device__ __forceinline__ f32x4 mfma16(s16x8 a, s16x8 b, f32x4 c) {
  return __builtin_amdgcn_mfma_f32_16x16x32_bf16(a, b, c, 0, 0, 0);
}
static __device__ __forceinline__ f32x16 mfma32(s16x8 a, s16x8 b, f32x16 c) {
  return __builtin_amdgcn_mfma_f32_32x32x16_bf16(a, b, c, 0, 0, 0);
}
static __device__ __forceinline__ int cvtpk(float lo, float hi) {
  int r;
  asm("v_cvt_pk_bf16_f32 %0, %1, %2" : "=v"(r) : "v"(lo), "v"(hi));
  return r;
}
static __device__ __forceinline__ void gload_lds16(const ushort* g, ushort* l) {
  __builtin_amdgcn_global_load_lds(
      (const __attribute__((address_space(1))) void*)g,
      (__attribute__((address_space(3))) void*)l, 16, 0, 0);
}

// ---------------------------------------------------------------------------
// Fused convert: inputs -> bf16, 4 weights transposed -> bf16, and straight
// bf16 copies of the Wpkv halves (Wpk_bf, Wpv_bf) for the qw / Wcomb paths.
// grid: 4704 input + 1152 transpose (nx24 x ky12 x wid4) + 1152 straight.
// ---------------------------------------------------------------------------
__global__ __launch_bounds__(256)
void cvt_all(const float* __restrict__ xq, const float* __restrict__ xk,
             ushort* __restrict__ xqbf, ushort* __restrict__ xkbf,
             const float* __restrict__ Wq, const float* __restrict__ Wkv,
             const float* __restrict__ Wpq, const float* __restrict__ Wproj,
             const float* __restrict__ Wpkv,
             ushort* __restrict__ WqT, ushort* __restrict__ WkvT,
             ushort* __restrict__ WpqT, ushort* __restrict__ WprT,
             ushort* __restrict__ Wpk_bf, ushort* __restrict__ Wpv_bf,
             int n4) {
  __shared__ float T[64][65];
  const int blk = blockIdx.x;
  const int tid = threadIdx.x;

  if (blk < 4704) {             // input conversion
    int i = blk*256 + tid;
    const float* src; ushort* dst; int j;
    if (i < n4)        { src = xq; dst = xqbf; j = i; }
    else               { src = xk; dst = xkbf; j = i - n4; }
    float4 v = ((const float4*)src)[j];
    ushort4 o; o.x = f2bf(v.x); o.y = f2bf(v.y); o.z = f2bf(v.z); o.w = f2bf(v.w);
    ((ushort4*)dst)[j] = o;
    return;
  }

  if (blk < 5856) {             // weight transpose (4 weights)
    int idx = blk - 4704;
    const int wid = idx / 288; idx %= 288;
    const int ky = idx / 24;
    const int nx = idx % 24;
    const float* W; ushort* WT; int N;
    switch (wid) {
      case 0: W = Wq;    WT = WqT;   N = DIM;   break;
      case 1: W = Wkv;   WT = WkvT;  N = 2*DIM; break;
      case 2: W = Wpq;   WT = WpqT;  N = DIM;   break;
      default: W = Wproj; WT = WprT; N = DIM;   break;
    }
    if (nx >= N/64) return;
    #pragma unroll
    for (int it = 0; it < 4; it++) {
      int id2 = it*256 + tid;
      int r = id2 >> 4, c4 = (id2 & 15) << 2;
      float4 v = *(const float4*)&W[(size_t)(ky*64 + r)*N + nx*64 + c4];
      T[r][c4+0] = v.x; T[r][c4+1] = v.y; T[r][c4+2] = v.z; T[r][c4+3] = v.w;
    }
    __syncthreads();
    #pragma unroll
    for (int it = 0; it < 4; it++) {
      int id2 = it*256 + tid;
      int n = id2 >> 4, k4 = (id2 & 15) << 2;
      ushort4 o;
      o.x = f2bf(T[k4+0][n]); o.y = f2bf(T[k4+1][n]);
      o.z = f2bf(T[k4+2][n]); o.w = f2bf(T[k4+3][n]);
      *(ushort4*)&WT[(size_t)(nx*64 + n)*DIM + ky*64 + k4] = o;
    }
    return;
  }

  // straight bf16 copies of Wpkv halves: Wpk_bf / Wpv_bf [768][768]
  {
    int id2 = blk - 5856;            // 0..1151
    int half = id2 / 576;
    int e = (id2 % 576)*256 + tid;   // float4 index within 768x768
    int r = e / 192;
    int c4 = (e % 192) * 4;
    float4 v = *(const float4*)&Wpkv[(size_t)r*(2*DIM) + half*DIM + c4];
    ushort4 o; o.x = f2bf(v.x); o.y = f2bf(v.y); o.z = f2bf(v.z); o.w = f2bf(v.w);
    ushort* dst = half ? Wpv_bf : Wpk_bf;
    *(ushort4*)&dst[(size_t)r*DIM + c4] = o;
  }
}

// Vt[(b,f,h)][64][224] bf16, zero-padded n>=196. grid = 192
__global__ __launch_bounds__(256)
void vtrans(const ushort* __restrict__ kvbf, ushort* __restrict__ Vt) {
  __shared__ ushort Vl[NTOK][72];
  const int x = blockIdx.x;
  const int h = x % NH, f = (x / NH) % FR, b = x / (NH*FR);
  const int tid = threadIdx.x;
  for (int idx = tid; idx < NTOK*16; idx += 256) {
    int n = idx >> 4, c4 = (idx & 15) << 2;
    const ushort* p = kvbf + (size_t)(b*SEQ + f*NTOK + n)*(2*DIM) + DIM + h*HD + c4;
    *(ushort4*)&Vl[n][c4] = *(const ushort4*)p;
  }
  __syncthreads();
  ushort* vb = Vt + (size_t)x * (HD*224);
  for (int idx = tid; idx < 64*56; idx += 256) {
    int d = idx / 56, n4 = (idx % 56) << 2;
    ushort4 o;
    o.x = (n4+0 < NTOK) ? Vl[n4+0][d] : (ushort)0;
    o.y = (n4+1 < NTOK) ? Vl[n4+1][d] : (ushort)0;
    o.z = (n4+2 < NTOK) ? Vl[n4+2][d] : (ushort)0;
    o.w = (n4+3 < NTOK) ? Vl[n4+3][d] : (ushort)0;
    *(ushort4*)&vb[(size_t)d*224 + n4] = o;
  }
}

// ---------------------------------------------------------------------------
// Merged q+kv projection, 128x128 tiles. grid (18, 25) = 450 blocks >= CU
// count (R10-proven best config).
// bx<6: qbf = 0.125*(xq@Wq) cols bx*128; else kvbf = xk@Wkv cols (bx-6)*128.
// ---------------------------------------------------------------------------
__global__ __launch_bounds__(256)
void proj_pair(const ushort* __restrict__ xqbf, const ushort* __restrict__ xkbf,
               const ushort* __restrict__ WqT, const ushort* __restrict__ WkvT,
               ushort* __restrict__ qbf, ushort* __restrict__ kvbf)
{
  __shared__ ushort As[128][32];
  __shared__ ushort Bs[128][32];
  const int bx = blockIdx.x, by = blockIdx.y;
  const ushort* A; const ushort* Bt; ushort* C; int N, col0; float scale;
  if (bx < 6) { A = xqbf; Bt = WqT;  C = qbf;  N = DIM;   col0 = bx*128;     scale = 0.125f; }
  else        { A = xkbf; Bt = WkvT; C = kvbf; N = 2*DIM; col0 = (bx-6)*128; scale = 1.0f; }

  const int tid = threadIdx.x;
  const int w = tid >> 6, lane = tid & 63;
  const int lq = lane & 15, quad = lane >> 4;
  const int wr = (w >> 1) * 64, wc = (w & 1) * 64;
  const int lrow = tid >> 2, lcol = (tid & 3) << 3;

  int ar0 = by*128 + lrow;       if (ar0 > MTOT-1) ar0 = MTOT-1;
  int ar1 = by*128 + 64 + lrow;  if (ar1 > MTOT-1) ar1 = MTOT-1;
  const size_t aoff0 = (size_t)ar0*DIM + lcol;
  const size_t aoff1 = (size_t)ar1*DIM + lcol;
  const size_t boff0 = (size_t)(col0 + lrow)*DIM + lcol;
  const size_t boff1 = (size_t)(col0 + 64 + lrow)*DIM + lcol;

  f32x4 acc[4][4] = {};
  for (int k0 = 0; k0 < DIM; k0 += 32) {
    __syncthreads();
    gload_lds16(A  + aoff0 + k0, &As[w*16][0]);
    gload_lds16(A  + aoff1 + k0, &As[64 + w*16][0]);
    gload_lds16(Bt + boff0 + k0, &Bs[w*16][0]);
    gload_lds16(Bt + boff1 + k0, &Bs[64 + w*16][0]);
    __syncthreads();
    s16x8 af[4], bw[4];
    #pragma unroll
    for (int i = 0; i < 4; i++) af[i] = *(const s16x8*)&As[wr + i*16 + lq][quad*8];
    #pragma unroll
    for (int j = 0; j < 4; j++) bw[j] = *(const s16x8*)&Bs[wc + j*16 + lq][quad*8];
    #pragma unroll
    for (int i = 0; i < 4; i++)
      #pragma unroll
      for (int j = 0; j < 4; j++)
        acc[i][j] = mfma16(af[i], bw[j], acc[i][j]);
  }

  #pragma unroll
  for (int i = 0; i < 4; i++) {
    #pragma unroll
    for (int r = 0; r < 4; r++) {
      int row = by*128 + wr + i*16 + quad*4 + r;
      if (row < MTOT) {
        #pragma unroll
        for (int j = 0; j < 4; j++)
          C[(size_t)row*N + col0 + wc + j*16 + lq] = f2bf(acc[i][j][r] * scale);
      }
    }
  }
}

// ---------------------------------------------------------------------------
// 128x64-tile GEMM (R8-proven). grid (N/64, ceil(M/128)). K=768.
// 300 blocks for the M=3136 out-proj keeps grid >= CU count (R9 lesson).
// BF16OUT: C is ushort bf16; else float.
// ---------------------------------------------------------------------------
template<bool BIAS, bool BF16OUT>
__global__ __launch_bounds__(256)
void gemm64(const ushort* __restrict__ A, const ushort* __restrict__ Bt,
            void* __restrict__ Cv, const float* __restrict__ bias,
            int M, int N, float scale)
{
  __shared__ ushort As[128][32];
  __shared__ ushort Bs[64][32];
  const int bx = blockIdx.x, by = blockIdx.y;
  const int tid = threadIdx.x;
  const int w = tid >> 6, lane = tid & 63;
  const int lq = lane & 15, quad = lane >> 4;
  const int lrow = tid >> 2, lcol = (tid & 3) << 3;
  const int col0 = bx*64;

  int ar0 = by*128 + lrow;       if (ar0 > M-1) ar0 = M-1;
  int ar1 = by*128 + 64 + lrow;  if (ar1 > M-1) ar1 = M-1;
  const size_t aoff0 = (size_t)ar0*DIM + lcol;
  const size_t aoff1 = (size_t)ar1*DIM + lcol;
  const size_t boff = (size_t)(col0 + lrow)*DIM + lcol;

  f32x4 acc[2][4] = {};
  for (int k0 = 0; k0 < DIM; k0 += 32) {
    __syncthreads();
    gload_lds16(A  + aoff0 + k0, &As[w*16][0]);
    gload_lds16(A  + aoff1 + k0, &As[64 + w*16][0]);
    gload_lds16(Bt + boff  + k0, &Bs[w*16][0]);
    __syncthreads();
    s16x8 af[2], bw[4];
    #pragma unroll
    for (int i = 0; i < 2; i++) af[i] = *(const s16x8*)&As[w*32 + i*16 + lq][quad*8];
    #pragma unroll
    for (int j = 0; j < 4; j++) bw[j] = *(const s16x8*)&Bs[j*16 + lq][quad*8];
    #pragma unroll
    for (int i = 0; i < 2; i++)
      #pragma unroll
      for (int j = 0; j < 4; j++)
        acc[i][j] = mfma16(af[i], bw[j], acc[i][j]);
  }

  #pragma unroll
  for (int i = 0; i < 2; i++) {
    #pragma unroll
    for (int r = 0; r < 4; r++) {
      int row = by*128 + w*32 + i*16 + quad*4 + r;
      if (row < M) {
        #pragma unroll
        for (int j = 0; j < 4; j++) {
          int col = col0 + j*16 + lq;
          float v = acc[i][j][r] * scale;
          if (BIAS) v += bias[col];
          if (BF16OUT) ((ushort*)Cv)[(size_t)row*N + col] = f2bf(v);
          else         ((float*)Cv)[(size_t)row*N + col] = v;
        }
      }
    }
  }
}

// ---------------------------------------------------------------------------
// FUSED q2 + qw kernel. grid (12 = head, 25 Mtiles).
// Phase 1: q2 tile = 0.125*(x_diag @ Wpq) cols h*64..+63  (K=768, DIAG gather)
//          -> parked in LDS q2s[128][72] bf16 (same-wave rows only).
// Phase 2: qw[row][h][c] = sum_dd q2[row][dd]*Wpk[c][h*64+dd] for c in 12
//          64-wide tiles (K=64, Bs restaged per 32-chunk, 1 gload/step).
// ---------------------------------------------------------------------------
__global__ __launch_bounds__(256)
void q2qw(const ushort* __restrict__ x, const ushort* __restrict__ WpqT,
          const ushort* __restrict__ Wpk, ushort* __restrict__ qw)
{
  __shared__ ushort As[128][32];
  __shared__ ushort Bs[64][32];
  __shared__ ushort q2s[128][72];
  const int h = blockIdx.x, by = blockIdx.y;
  const int tid = threadIdx.x;
  const int w = tid >> 6, lane = tid & 63;
  const int lq = lane & 15, quad = lane >> 4;
  const int lrow = tid >> 2, lcol = (tid & 3) << 3;

  int ar0 = by*128 + lrow;       if (ar0 > MTOT-1) ar0 = MTOT-1;
  int ar1 = by*128 + 64 + lrow;  if (ar1 > MTOT-1) ar1 = MTOT-1;
  const int f0 = (ar0 % SEQ) / NTOK, f1 = (ar1 % SEQ) / NTOK;
  const size_t aoff0 = ((size_t)ar0*FR + f0)*DIM + lcol;
  const size_t aoff1 = ((size_t)ar1*FR + f1)*DIM + lcol;
  const size_t boff  = (size_t)(h*64 + lrow)*DIM + lcol;

  // ---- phase 1: q2 tile (DIAG A-gather, K=768)
  f32x4 acc[2][4] = {};
  for (int k0 = 0; k0 < DIM; k0 += 32) {
    __syncthreads();
    gload_lds16(x    + aoff0 + k0, &As[w*16][0]);
    gload_lds16(x    + aoff1 + k0, &As[64 + w*16][0]);
    gload_lds16(WpqT + boff  + k0, &Bs[w*16][0]);
    __syncthreads();
    s16x8 af[2], bw[4];
    #pragma unroll
    for (int i = 0; i < 2; i++) af[i] = *(const s16x8*)&As[w*32 + i*16 + lq][quad*8];
    #pragma unroll
    for (int j = 0; j < 4; j++) bw[j] = *(const s16x8*)&Bs[j*16 + lq][quad*8];
    #pragma unroll
    for (int i = 0; i < 2; i++)
      #pragma unroll
      for (int j = 0; j < 4; j++)
        acc[i][j] = mfma16(af[i], bw[j], acc[i][j]);
  }

  // ---- park q2 tile in LDS bf16 (scale 0.125); rows are wave-local
  #pragma unroll
  for (int i = 0; i < 2; i++)
    #pragma unroll
    for (int r = 0; r < 4; r++) {
      int row = w*32 + i*16 + quad*4 + r;
      #pragma unroll
      for (int j = 0; j < 4; j++)
        q2s[row][j*16 + lq] = f2bf(acc[i][j][r] * 0.125f);
    }

  // ---- phase 2: qw tiles over c (12 x 64 cols), K=64 from q2s
  for (int ct = 0; ct < 12; ++ct) {
    f32x4 acc2[2][4] = {};
    #pragma unroll
    for (int k0 = 0; k0 < 64; k0 += 32) {
      __syncthreads();
      gload_lds16(Wpk + (size_t)(ct*64 + lrow)*DIM + h*HD + k0 + lcol, &Bs[w*16][0]);
      __syncthreads();
      s16x8 af[2], bw[4];
      #pragma unroll
      for (int i = 0; i < 2; i++)
        af[i] = *(const s16x8*)&q2s[w*32 + i*16 + lq][k0 + quad*8];
      #pragma unroll
      for (int j = 0; j < 4; j++) bw[j] = *(const s16x8*)&Bs[j*16 + lq][quad*8];
      #pragma unroll
      for (int i = 0; i < 2; i++)
        #pragma unroll
        for (int j = 0; j < 4; j++)
          acc2[i][j] = mfma16(af[i], bw[j], acc2[i][j]);
    }
    #pragma unroll
    for (int i = 0; i < 2; i++) {
      #pragma unroll
      for (int r = 0; r < 4; r++) {
        int row = by*128 + w*32 + i*16 + quad*4 + r;
        if (row < MTOT) {
          #pragma unroll
          for (int j = 0; j < 4; j++)
            qw[(size_t)row*(NH*DIM) + h*DIM + ct*64 + j*16 + lq] = f2bf(acc2[i][j][r]);
        }
      }
    }
  }
}

// ---------------------------------------------------------------------------
// Fused logits + softmax + x-aggregation. grid 1568 (2 t / block).
// R10 lesson: the 4-token version used 124 KB LDS -> 1 block/CU -> no
// latency hiding for its 123 KB staging. This version: 62.6 KB -> 2
// blocks/CU, K-range split across wave pairs (waves 0-1: ks 0-11 of token
// 0/1; waves 2-3: ks 12-23), partial logits combined through 1.5 KB LDS.
// Same 264-chunk bank padding; softmax lane mapping unchanged.
// ---------------------------------------------------------------------------
__global__ __launch_bounds__(256)
void logits_sa(const ushort* __restrict__ qw, const ushort* __restrict__ x,
               float* __restrict__ attn2, ushort* __restrict__ xa)
{
  __shared__ ushort xs[2*8*792];       // 24.75 KB [tf][ch*264+cc]
  __shared__ ushort qws[2*12*792];     // 37.125 KB [th][ch*264+cc]
  __shared__ float  part[2][2][8][12]; // [kh][tt][f][h] 1.5 KB
  __shared__ float  a_s[2][NH][FR];    // 0.75 KB
  const int tid = threadIdx.x;
  const int t0 = blockIdx.x * 2;

  #pragma unroll
  for (int r = 0; r < 6; ++r) {        // stage x: 2t*8f*96 vec8
    int id = r*256 + tid;
    int tf = id / 96, v8 = id % 96;
    int ch = v8 >> 5, cc = v8 & 31;
    s16x8 v = *(const s16x8*)(x + ((size_t)(t0 + (tf >> 3))*FR + (tf & 7))*DIM + v8*8);
    *(s16x8*)&xs[tf*792 + ch*264 + cc*8] = v;
  }
  #pragma unroll
  for (int r = 0; r < 9; ++r) {        // stage qw: 2t*12h*96 vec8
    int id = r*256 + tid;
    int th = id / 96, v8 = id % 96;
    int ch = v8 >> 5, cc = v8 & 31;
    s16x8 v = *(const s16x8*)(qw + (size_t)(t0 + th/12)*(NH*DIM) + (th%12)*DIM + v8*8);
    *(s16x8*)&qws[th*792 + ch*264 + cc*8] = v;
  }
  __syncthreads();

  const int w = tid >> 6, lane = tid & 63;
  const int lq = lane & 15, quad = lane >> 4;
  const int tt = w & 1, kh = w >> 1;          // token, k-half per wave
  const int fr = lq & 7;                      // A row (rows 8-15 duplicate f)
  const int hc = (lq < 12) ? lq : 0;          // B col clamp
  f32x4 acc = {};
  #pragma unroll
  for (int k = 0; k < 12; ++k) {
    int ks = kh*12 + k;
    int ch = ks >> 3, cc = (ks & 7) * 32;
    s16x8 a = *(const s16x8*)&xs[(tt*8 + fr)*792 + ch*264 + cc + quad*8];
    s16x8 b = *(const s16x8*)&qws[(tt*12 + hc)*792 + ch*264 + cc + quad*8];
    acc = mfma16(a, b, acc);
  }
  if (quad < 2 && lq < 12) {
    #pragma unroll
    for (int r = 0; r < 4; ++r)
      part[kh][tt][quad*4 + r][lq] = acc[r];
  }
  __syncthreads();

  // combine halves + softmax over f (waves 0-1 only; shfl_xor 16 pairs
  // quad0<->quad1 within lanes 0..31 exactly as the proven 4t version)
  if (kh == 0) {
    float l0 = part[0][tt][quad*4 + 0][hc] + part[1][tt][quad*4 + 0][hc];
    float l1 = part[0][tt][quad*4 + 1][hc] + part[1][tt][quad*4 + 1][hc];
    float l2 = part[0][tt][quad*4 + 2][hc] + part[1][tt][quad*4 + 2][hc];
    float l3 = part[0][tt][quad*4 + 3][hc] + part[1][tt][quad*4 + 3][hc];
    float m4 = fmaxf(fmaxf(l0, l1), fmaxf(l2, l3));
    float M = fmaxf(m4, __shfl_xor(m4, 16));
    float e0 = __expf(l0-M), e1 = __expf(l1-M);
    float e2 = __expf(l2-M), e3 = __expf(l3-M);
    float s4 = (e0+e1)+(e2+e3);
    float S = s4 + __shfl_xor(s4, 16);
    float inv = 1.0f / S;
    if (quad < 2 && lq < 12) {
      int gt = t0 + tt;
      int b = gt / SEQ, sI = gt % SEQ;
      float4 av; av.x = e0*inv; av.y = e1*inv; av.z = e2*inv; av.w = e3*inv;
      *(float4*)(attn2 + ((size_t)(b*NH + hc)*SEQ + sI)*FR + quad*4) = av;
      a_s[tt][hc][quad*4+0] = av.x; a_s[tt][hc][quad*4+1] = av.y;
      a_s[tt][hc][quad*4+2] = av.z; a_s[tt][hc][quad*4+3] = av.w;
    }
  }
  __syncthreads();

  // xa[t,c] = sum_f a_s[t][h(c)][f] * x[t,f,c]; x read from LDS
  if (tid < 192) {
    int tt2 = tid / 96, v8 = tid % 96;
    int ch = v8 >> 5, cc = v8 & 31;
    int h = v8 >> 3;
    float av[8] = {};
    #pragma unroll
    for (int f = 0; f < FR; ++f) {
      float a = a_s[tt2][h][f];
      s16x8 xv = *(const s16x8*)&xs[(tt2*8 + f)*792 + ch*264 + cc*8];
      #pragma unroll
      for (int e = 0; e < 8; ++e) av[e] += a * bf2f((ushort)xv[e]);
    }
    ushort4 o0, o1;
    o0.x = f2bf(av[0]); o0.y = f2bf(av[1]); o0.z = f2bf(av[2]); o0.w = f2bf(av[3]);
    o1.x = f2bf(av[4]); o1.y = f2bf(av[5]); o1.z = f2bf(av[6]); o1.w = f2bf(av[7]);
    ushort* op = xa + (size_t)(t0 + tt2)*DIM + v8*8;
    *(ushort4*)op = o0; *(ushort4*)(op + 4) = o1;
  }
}

// ---------------------------------------------------------------------------
// Stage 1, 32x32 MFMA, swapped operands (S^T = K.Q^T), in-register P.
// (unchanged from R2-verified version)
// ---------------------------------------------------------------------------
__global__ __launch_bounds__(256)
void stage1_mfma(const ushort* __restrict__ qbf, const ushort* __restrict__ kvbf,
                 const ushort* __restrict__ Vt, ushort* __restrict__ x)
{
  __shared__ ushort sh[208*64];   // 26624 B: K tile, then per-wave X transpose

  const int bh = blockIdx.x;   // 0..23
  const int f  = blockIdx.y;   // 0..7
  const int qt = blockIdx.z;   // 0..12
  const int b = bh / NH, h = bh % NH;
  const int tid = threadIdx.x;
  const int w = tid >> 6, lane = tid & 63;
  const int l31 = lane & 31, hl = lane >> 5;

  const ushort* kbase = kvbf + ((size_t)b*SEQ + f*NTOK)*(2*DIM) + h*HD;
  #pragma unroll
  for (int p = 0; p < 6; ++p) {
    const int c = w*6 + p;                         // 8-row chunk, rows < 192
    const int row = c*8 + (lane >> 3);
    const ushort* src = kbase + (size_t)row*(2*DIM)
                      + (((lane & 7) ^ (lane >> 3)) << 3);
    gload_lds16(src, &sh[c*512]);
  }
  { // rows 192..207: 192..195 from global, 196..207 zero (same swizzle)
    const int row = 192 + (tid >> 4);
    const int c4  = (tid & 15) << 2;
    ushort4 v; v.x = 0; v.y = 0; v.z = 0; v.w = 0;
    if (row < NTOK)
      v = *(const ushort4*)(kbase + (size_t)row*(2*DIM) + c4);
    *(ushort4*)&sh[row*64 + ((((c4 >> 3) ^ (row & 7)) << 3) | (c4 & 7))] = v;
  }

  int qrow = qt*128 + w*32 + l31; if (qrow > SEQ-1) qrow = SEQ-1;
  const ushort* qp = qbf + ((size_t)b*SEQ + qrow)*DIM + h*HD + hl*8;
  const s16x8 bq0 = *(const s16x8*)(qp);
  const s16x8 bq1 = *(const s16x8*)(qp + 16);
  const s16x8 bq2 = *(const s16x8*)(qp + 32);
  const s16x8 bq3 = *(const s16x8*)(qp + 48);

  __syncthreads();

  f32x16 acc[7];
  {
    f32x16 z = {};
    #pragma unroll
    for (int nt = 0; nt < 7; ++nt) acc[nt] = z;
  }
  const int sx = l31 & 7;
  #pragma unroll
  for (int nt = 0; nt < 7; ++nt) {
    const int rl = (nt == 6) ? (l31 & 15) : l31;   // keep tile-6 A-reads in bounds
    const int rbase = (nt*32 + rl)*64;
    acc[nt] = mfma32(*(const s16x8*)&sh[rbase + (((0 + hl) ^ sx) << 3)], bq0, acc[nt]);
    acc[nt] = mfma32(*(const s16x8*)&sh[rbase + (((2 + hl) ^ sx) << 3)], bq1, acc[nt]);
    acc[nt] = mfma32(*(const s16x8*)&sh[rbase + (((4 + hl) ^ sx) << 3)], bq2, acc[nt]);
    acc[nt] = mfma32(*(const s16x8*)&sh[rbase + (((6 + hl) ^ sx) << 3)], bq3, acc[nt]);
  }

  __syncthreads();   // all K reads done -> sh reusable for X transpose

  float s0 = 0.f, s1 = 0.f, s2 = 0.f, s3 = 0.f;
  #pragma unroll
  for (int nt = 0; nt < 7; ++nt) {
    #pragma unroll
    for (int g = 0; g < 16; ++g) {
      float e;
      if (nt == 6) {
        if (g < 4) { e = __expf(acc[6][g]); if (hl) e = 0.f; }  // n=192..195 only
        else e = 0.f;
      } else {
        e = __expf(acc[nt][g]);
      }
      acc[nt][g] = e;
      if ((g & 3) == 0) s0 += e; else if ((g & 3) == 1) s1 += e;
      else if ((g & 3) == 2) s2 += e; else s3 += e;
    }
  }
  float sum = (s0 + s1) + (s2 + s3);
  sum += __shfl_xor(sum, 32);
  const float sinv = 1.0f / sum;

  f32x16 o0, o1;
  { f32x16 z = {}; o0 = z; o1 = z; }
  const ushort* vb = Vt + ((size_t)((b*FR + f)*NH + h)) * (HD*224);
  const ushort* vr0 = vb + (size_t)l31*224 + hl*8;
  const ushort* vr1 = vr0 + 32*224;
  #pragma unroll
  for (int nt = 0; nt < 7; ++nt) {
    #pragma unroll
    for (int kh = 0; kh < 2; ++kh) {
      int w0 = cvtpk(acc[nt][8*kh+0], acc[nt][8*kh+1]);
      int w1 = cvtpk(acc[nt][8*kh+2], acc[nt][8*kh+3]);
      int w2 = cvtpk(acc[nt][8*kh+4], acc[nt][8*kh+5]);
      int w3 = cvtpk(acc[nt][8*kh+6], acc[nt][8*kh+7]);
      asm("v_permlane32_swap_b32 %0, %1" : "+v"(w0), "+v"(w2));
      asm("v_permlane32_swap_b32 %0, %1" : "+v"(w1), "+v"(w3));
      union { i32x4 i; s16x8 s; } u;
      u.i.x = w0; u.i.y = w1; u.i.z = w2; u.i.w = w3;
      const int ks = nt*2 + kh;
      const s16x8 va0 = *(const s16x8*)(vr0 + ks*16);
      const s16x8 va1 = *(const s16x8*)(vr1 + ks*16);
      o0 = mfma32(va0, u.s, o0);
      o1 = mfma32(va1, u.s, o1);
    }
  }

  ushort* XT = sh + w*2048;
  #pragma unroll
  for (int dt = 0; dt < 2; ++dt) {
    #pragma unroll
    for (int c = 0; c < 4; ++c) {
      #pragma unroll
      for (int rp = 0; rp < 2; ++rp) {
        const float lo = (dt ? o1[4*c + 2*rp]     : o0[4*c + 2*rp])     * sinv;
        const float hi = (dt ? o1[4*c + 2*rp + 1] : o0[4*c + 2*rp + 1]) * sinv;
        const int word = cvtpk(lo, hi);
        const int d = dt*32 + 8*c + 4*hl + 2*rp;
        *(uint*)&XT[l31*64 + (((d >> 3) ^ (l31 & 7)) << 3) + (d & 7)] = (uint)word;
      }
    }
  }
  #pragma unroll
  for (int it = 0; it < 4; ++it) {
    const int q = it*8 + (lane >> 3);
    const int g = lane & 7;
    s16x8 xv = *(const s16x8*)&XT[q*64 + ((g ^ (q & 7)) << 3)];
    const int s = qt*128 + w*32 + q;
    if (s < SEQ) {
      ushort* xp = x + (((size_t)b*SEQ + s)*FR + f)*DIM + h*HD + g*8;
      *(s16x8*)xp = xv;
    }
  }
}

// ---------------------------------------------------------------------------
// Workspace (ushort units; ~123 MB used; harness memsets ~268 MB of ws):
//  xbf | kvbf | qbf | xqbf (Vt alias) | xkbf (xa alias) |
//  WqT | WkvT | WpqT | WprT | Wpk_bf | Wpv_bf | WcombT | qw (57.8 MB full)
// ---------------------------------------------------------------------------
extern "C" void kernel_launch(void* const* d_in, const int* in_sizes, int n_in,
                              void* d_out, int out_size, void* d_ws, size_t ws_size,
                              hipStream_t stream) {
  const float* xq    = (const float*)d_in[0];
  const float* xk    = (const float*)d_in[1];
  const float* Wq    = (const float*)d_in[2];
  const float* Wkv   = (const float*)d_in[3];
  const float* Wpq   = (const float*)d_in[4];
  const float* Wpkv  = (const float*)d_in[5];
  const float* Wproj = (const float*)d_in[6];
  const float* bproj = (const float*)d_in[7];

  float* out   = (float*)d_out;
  float* attn2 = out + (size_t)MTOT*DIM;

  ushort* ws     = (ushort*)d_ws;
  ushort* xbf    = ws;
  ushort* kvbf   = xbf + (size_t)MTOT*FR*DIM;
  ushort* qbf    = kvbf + (size_t)MTOT*2*DIM;
  ushort* xqbf   = qbf + (size_t)MTOT*DIM;
  ushort* xkbf   = xqbf + (size_t)MTOT*DIM;
  ushort* Vt     = xqbf;                        // alias (dead post-proj)
  ushort* xa     = xkbf;                        // alias (dead post-proj)
  ushort* WqT    = xkbf + (size_t)MTOT*DIM;
  ushort* WkvT   = WqT  + (size_t)DIM*DIM;
  ushort* WpqT   = WkvT + (size_t)2*DIM*DIM;
  ushort* WprT   = WpqT + (size_t)DIM*DIM;
  ushort* Wpk_bf = WprT + (size_t)DIM*DIM;
  ushort* Wpv_bf = Wpk_bf + (size_t)DIM*DIM;
  ushort* WcombT = Wpv_bf + (size_t)DIM*DIM;
  ushort* qw     = WcombT + (size_t)DIM*DIM;    // [3136][12][768] bf16, 57.8 MB

  dim3 blk(256);
  const int n4 = MTOT*DIM/4;

  cvt_all<<<dim3(4704 + 1152 + 1152), blk, 0, stream>>>(
      xq, xk, xqbf, xkbf, Wq, Wkv, Wpq, Wproj, Wpkv,
      WqT, WkvT, WpqT, WprT, Wpk_bf, Wpv_bf, n4);

  // WcombT[n][k] = sum_m Wproj[m][n]*Wpv[k][m]  (fused z+out projection)
  gemm64<false,true><<<dim3(12, 6), blk, 0, stream>>>(
      WprT, Wpv_bf, WcombT, nullptr, DIM, DIM, 1.0f);

  proj_pair<<<dim3(18, (MTOT+127)/128), blk, 0, stream>>>(
      xqbf, xkbf, WqT, WkvT, qbf, kvbf);
  vtrans<<<dim3(BDIM*FR*NH), blk, 0, stream>>>(kvbf, Vt);
  stage1_mfma<<<dim3(BDIM*NH, FR, (SEQ+127)/128), blk, 0, stream>>>(qbf, kvbf, Vt, xbf);

  // fused q2 + qw (replaces q2 gemm + qwgemm; no q2bf round-trip)
  q2qw<<<dim3(12, 25), blk, 0, stream>>>(xbf, WpqT, Wpk_bf, qw);

  logits_sa<<<dim3(MTOT/2), blk, 0, stream>>>(qw, xbf, attn2, xa);

  // out = xa @ Wcomb + bproj  (128x64 tiles -> 300 blocks, R10-proven)
  gemm64<true,false><<<dim3(12, (MTOT+127)/128), blk, 0, stream>>>(
      xa, WcombT, out, bproj, MTOT, DIM, 1.0f);
}

// Round 12
// 236.195 us; speedup vs baseline: 1.0697x; 1.0032x over previous
//
#include <hip/hip_runtime.h>

#define BDIM 2
#define SEQ  1568
#define DIM  768
#define NH   12
#define FR   8
#define NTOK 196
#define HD   64
#define MTOT (BDIM*SEQ)   // 3136 token rows
#define M2   (MTOT*FR)    // 25088 (t,f) rows

typedef __attribute__((ext_vector_type(8))) short s16x8;
typedef __attribute__((ext_vector_type(4))) float f32x4;
typedef __attribute__((ext_vector_type(16))) float f32x16;
typedef __attribute__((ext_vector_type(4))) int i32x4;

static __device__ __forceinline__ float bf2f(ushort u) {
  return __uint_as_float(((unsigned)u) << 16);
}
static __device__ __forceinline__ ushort f2bf(float f) {
  unsigned u = __float_as_uint(f);
  unsigned r = (u + 0x7fffu + ((u >> 16) & 1u)) >> 16;
  return (ushort)r;
}
static __device__ __forceinline__ f32x4 mfma16(s16x8 a, s16x8 b, f32x4 c) {
  return __builtin_amdgcn_mfma_f32_16x16x32_bf16(a, b, c, 0, 0, 0);
}
static __device__ __forceinline__ f32x16 mfma32(s16x8 a, s16x8 b, f32x16 c) {
  return __builtin_amdgcn_mfma_f32_32x32x16_bf16(a, b, c, 0, 0, 0);
}
static __device__ __forceinline__ int cvtpk(float lo, float hi) {
  int r;
  asm("v_cvt_pk_bf16_f32 %0, %1, %2" : "=v"(r) : "v"(lo), "v"(hi));
  return r;
}
static __device__ __forceinline__ void gload_lds16(const ushort* g, ushort* l) {
  __builtin_amdgcn_global_load_lds(
      (const __attribute__((address_space(1))) void*)g,
      (__attribute__((address_space(3))) void*)l, 16, 0, 0);
}

// ---------------------------------------------------------------------------
// Fused convert: inputs -> bf16, 4 weights transposed -> bf16, and straight
// bf16 copies of the Wpkv halves (Wpk_bf, Wpv_bf) for the qw / Wcomb paths.
// grid: 4704 input + 1152 transpose (nx24 x ky12 x wid4) + 1152 straight.
// ---------------------------------------------------------------------------
__global__ __launch_bounds__(256)
void cvt_all(const float* __restrict__ xq, const float* __restrict__ xk,
             ushort* __restrict__ xqbf, ushort* __restrict__ xkbf,
             const float* __restrict__ Wq, const float* __restrict__ Wkv,
             const float* __restrict__ Wpq, const float* __restrict__ Wproj,
             const float* __restrict__ Wpkv,
             ushort* __restrict__ WqT, ushort* __restrict__ WkvT,
             ushort* __restrict__ WpqT, ushort* __restrict__ WprT,
             ushort* __restrict__ Wpk_bf, ushort* __restrict__ Wpv_bf,
             int n4) {
  __shared__ float T[64][65];
  const int blk = blockIdx.x;
  const int tid = threadIdx.x;

  if (blk < 4704) {             // input conversion
    int i = blk*256 + tid;
    const float* src; ushort* dst; int j;
    if (i < n4)        { src = xq; dst = xqbf; j = i; }
    else               { src = xk; dst = xkbf; j = i - n4; }
    float4 v = ((const float4*)src)[j];
    ushort4 o; o.x = f2bf(v.x); o.y = f2bf(v.y); o.z = f2bf(v.z); o.w = f2bf(v.w);
    ((ushort4*)dst)[j] = o;
    return;
  }

  if (blk < 5856) {             // weight transpose (4 weights)
    int idx = blk - 4704;
    const int wid = idx / 288; idx %= 288;
    const int ky = idx / 24;
    const int nx = idx % 24;
    const float* W; ushort* WT; int N;
    switch (wid) {
      case 0: W = Wq;    WT = WqT;   N = DIM;   break;
      case 1: W = Wkv;   WT = WkvT;  N = 2*DIM; break;
      case 2: W = Wpq;   WT = WpqT;  N = DIM;   break;
      default: W = Wproj; WT = WprT; N = DIM;   break;
    }
    if (nx >= N/64) return;
    #pragma unroll
    for (int it = 0; it < 4; it++) {
      int id2 = it*256 + tid;
      int r = id2 >> 4, c4 = (id2 & 15) << 2;
      float4 v = *(const float4*)&W[(size_t)(ky*64 + r)*N + nx*64 + c4];
      T[r][c4+0] = v.x; T[r][c4+1] = v.y; T[r][c4+2] = v.z; T[r][c4+3] = v.w;
    }
    __syncthreads();
    #pragma unroll
    for (int it = 0; it < 4; it++) {
      int id2 = it*256 + tid;
      int n = id2 >> 4, k4 = (id2 & 15) << 2;
      ushort4 o;
      o.x = f2bf(T[k4+0][n]); o.y = f2bf(T[k4+1][n]);
      o.z = f2bf(T[k4+2][n]); o.w = f2bf(T[k4+3][n]);
      *(ushort4*)&WT[(size_t)(nx*64 + n)*DIM + ky*64 + k4] = o;
    }
    return;
  }

  // straight bf16 copies of Wpkv halves: Wpk_bf / Wpv_bf [768][768]
  {
    int id2 = blk - 5856;            // 0..1151
    int half = id2 / 576;
    int e = (id2 % 576)*256 + tid;   // float4 index within 768x768
    int r = e / 192;
    int c4 = (e % 192) * 4;
    float4 v = *(const float4*)&Wpkv[(size_t)r*(2*DIM) + half*DIM + c4];
    ushort4 o; o.x = f2bf(v.x); o.y = f2bf(v.y); o.z = f2bf(v.z); o.w = f2bf(v.w);
    ushort* dst = half ? Wpv_bf : Wpk_bf;
    *(ushort4*)&dst[(size_t)r*DIM + c4] = o;
  }
}

// Vt[(b,f,h)][64][224] bf16, zero-padded n>=196. grid = 192
__global__ __launch_bounds__(256)
void vtrans(const ushort* __restrict__ kvbf, ushort* __restrict__ Vt) {
  __shared__ ushort Vl[NTOK][72];
  const int x = blockIdx.x;
  const int h = x % NH, f = (x / NH) % FR, b = x / (NH*FR);
  const int tid = threadIdx.x;
  for (int idx = tid; idx < NTOK*16; idx += 256) {
    int n = idx >> 4, c4 = (idx & 15) << 2;
    const ushort* p = kvbf + (size_t)(b*SEQ + f*NTOK + n)*(2*DIM) + DIM + h*HD + c4;
    *(ushort4*)&Vl[n][c4] = *(const ushort4*)p;
  }
  __syncthreads();
  ushort* vb = Vt + (size_t)x * (HD*224);
  for (int idx = tid; idx < 64*56; idx += 256) {
    int d = idx / 56, n4 = (idx % 56) << 2;
    ushort4 o;
    o.x = (n4+0 < NTOK) ? Vl[n4+0][d] : (ushort)0;
    o.y = (n4+1 < NTOK) ? Vl[n4+1][d] : (ushort)0;
    o.z = (n4+2 < NTOK) ? Vl[n4+2][d] : (ushort)0;
    o.w = (n4+3 < NTOK) ? Vl[n4+3][d] : (ushort)0;
    *(ushort4*)&vb[(size_t)d*224 + n4] = o;
  }
}

// ---------------------------------------------------------------------------
// Merged q+kv projection, 128x128 tiles. grid (18, 25) = 450 blocks >= CU
// count (R10-proven best config).
// bx<6: qbf = 0.125*(xq@Wq) cols bx*128; else kvbf = xk@Wkv cols (bx-6)*128.
// ---------------------------------------------------------------------------
__global__ __launch_bounds__(256)
void proj_pair(const ushort* __restrict__ xqbf, const ushort* __restrict__ xkbf,
               const ushort* __restrict__ WqT, const ushort* __restrict__ WkvT,
               ushort* __restrict__ qbf, ushort* __restrict__ kvbf)
{
  __shared__ ushort As[128][32];
  __shared__ ushort Bs[128][32];
  const int bx = blockIdx.x, by = blockIdx.y;
  const ushort* A; const ushort* Bt; ushort* C; int N, col0; float scale;
  if (bx < 6) { A = xqbf; Bt = WqT;  C = qbf;  N = DIM;   col0 = bx*128;     scale = 0.125f; }
  else        { A = xkbf; Bt = WkvT; C = kvbf; N = 2*DIM; col0 = (bx-6)*128; scale = 1.0f; }

  const int tid = threadIdx.x;
  const int w = tid >> 6, lane = tid & 63;
  const int lq = lane & 15, quad = lane >> 4;
  const int wr = (w >> 1) * 64, wc = (w & 1) * 64;
  const int lrow = tid >> 2, lcol = (tid & 3) << 3;

  int ar0 = by*128 + lrow;       if (ar0 > MTOT-1) ar0 = MTOT-1;
  int ar1 = by*128 + 64 + lrow;  if (ar1 > MTOT-1) ar1 = MTOT-1;
  const size_t aoff0 = (size_t)ar0*DIM + lcol;
  const size_t aoff1 = (size_t)ar1*DIM + lcol;
  const size_t boff0 = (size_t)(col0 + lrow)*DIM + lcol;
  const size_t boff1 = (size_t)(col0 + 64 + lrow)*DIM + lcol;

  f32x4 acc[4][4] = {};
  for (int k0 = 0; k0 < DIM; k0 += 32) {
    __syncthreads();
    gload_lds16(A  + aoff0 + k0, &As[w*16][0]);
    gload_lds16(A  + aoff1 + k0, &As[64 + w*16][0]);
    gload_lds16(Bt + boff0 + k0, &Bs[w*16][0]);
    gload_lds16(Bt + boff1 + k0, &Bs[64 + w*16][0]);
    __syncthreads();
    s16x8 af[4], bw[4];
    #pragma unroll
    for (int i = 0; i < 4; i++) af[i] = *(const s16x8*)&As[wr + i*16 + lq][quad*8];
    #pragma unroll
    for (int j = 0; j < 4; j++) bw[j] = *(const s16x8*)&Bs[wc + j*16 + lq][quad*8];
    #pragma unroll
    for (int i = 0; i < 4; i++)
      #pragma unroll
      for (int j = 0; j < 4; j++)
        acc[i][j] = mfma16(af[i], bw[j], acc[i][j]);
  }

  #pragma unroll
  for (int i = 0; i < 4; i++) {
    #pragma unroll
    for (int r = 0; r < 4; r++) {
      int row = by*128 + wr + i*16 + quad*4 + r;
      if (row < MTOT) {
        #pragma unroll
        for (int j = 0; j < 4; j++)
          C[(size_t)row*N + col0 + wc + j*16 + lq] = f2bf(acc[i][j][r] * scale);
      }
    }
  }
}

// ---------------------------------------------------------------------------
// 128x64-tile GEMM (R8-proven). grid (N/64, ceil(M/128)). K=768.
// 300 blocks for the M=3136 out-proj keeps grid >= CU count (R9 lesson).
// BF16OUT: C is ushort bf16; else float.
// ---------------------------------------------------------------------------
template<bool BIAS, bool BF16OUT>
__global__ __launch_bounds__(256)
void gemm64(const ushort* __restrict__ A, const ushort* __restrict__ Bt,
            void* __restrict__ Cv, const float* __restrict__ bias,
            int M, int N, float scale)
{
  __shared__ ushort As[128][32];
  __shared__ ushort Bs[64][32];
  const int bx = blockIdx.x, by = blockIdx.y;
  const int tid = threadIdx.x;
  const int w = tid >> 6, lane = tid & 63;
  const int lq = lane & 15, quad = lane >> 4;
  const int lrow = tid >> 2, lcol = (tid & 3) << 3;
  const int col0 = bx*64;

  int ar0 = by*128 + lrow;       if (ar0 > M-1) ar0 = M-1;
  int ar1 = by*128 + 64 + lrow;  if (ar1 > M-1) ar1 = M-1;
  const size_t aoff0 = (size_t)ar0*DIM + lcol;
  const size_t aoff1 = (size_t)ar1*DIM + lcol;
  const size_t boff = (size_t)(col0 + lrow)*DIM + lcol;

  f32x4 acc[2][4] = {};
  for (int k0 = 0; k0 < DIM; k0 += 32) {
    __syncthreads();
    gload_lds16(A  + aoff0 + k0, &As[w*16][0]);
    gload_lds16(A  + aoff1 + k0, &As[64 + w*16][0]);
    gload_lds16(Bt + boff  + k0, &Bs[w*16][0]);
    __syncthreads();
    s16x8 af[2], bw[4];
    #pragma unroll
    for (int i = 0; i < 2; i++) af[i] = *(const s16x8*)&As[w*32 + i*16 + lq][quad*8];
    #pragma unroll
    for (int j = 0; j < 4; j++) bw[j] = *(const s16x8*)&Bs[j*16 + lq][quad*8];
    #pragma unroll
    for (int i = 0; i < 2; i++)
      #pragma unroll
      for (int j = 0; j < 4; j++)
        acc[i][j] = mfma16(af[i], bw[j], acc[i][j]);
  }

  #pragma unroll
  for (int i = 0; i < 2; i++) {
    #pragma unroll
    for (int r = 0; r < 4; r++) {
      int row = by*128 + w*32 + i*16 + quad*4 + r;
      if (row < M) {
        #pragma unroll
        for (int j = 0; j < 4; j++) {
          int col = col0 + j*16 + lq;
          float v = acc[i][j][r] * scale;
          if (BIAS) v += bias[col];
          if (BF16OUT) ((ushort*)Cv)[(size_t)row*N + col] = f2bf(v);
          else         ((float*)Cv)[(size_t)row*N + col] = v;
        }
      }
    }
  }
}

// ---------------------------------------------------------------------------
// FUSED q2 + qw kernel. grid (12 = head, 25 Mtiles).
// Phase 1: q2 tile = 0.125*(x_diag @ Wpq) cols h*64..+63  (K=768, DIAG gather)
//          -> parked in LDS q2s[128][72] bf16 (same-wave rows only).
// Phase 2: qw[row][h][c] = sum_dd q2[row][dd]*Wpk[c][h*64+dd] for c in 12
//          64-wide tiles (K=64, Bs restaged per 32-chunk, 1 gload/step).
// ---------------------------------------------------------------------------
__global__ __launch_bounds__(256)
void q2qw(const ushort* __restrict__ x, const ushort* __restrict__ WpqT,
          const ushort* __restrict__ Wpk, ushort* __restrict__ qw)
{
  __shared__ ushort As[128][32];
  __shared__ ushort Bs[64][32];
  __shared__ ushort q2s[128][72];
  const int h = blockIdx.x, by = blockIdx.y;
  const int tid = threadIdx.x;
  const int w = tid >> 6, lane = tid & 63;
  const int lq = lane & 15, quad = lane >> 4;
  const int lrow = tid >> 2, lcol = (tid & 3) << 3;

  int ar0 = by*128 + lrow;       if (ar0 > MTOT-1) ar0 = MTOT-1;
  int ar1 = by*128 + 64 + lrow;  if (ar1 > MTOT-1) ar1 = MTOT-1;
  const int f0 = (ar0 % SEQ) / NTOK, f1 = (ar1 % SEQ) / NTOK;
  const size_t aoff0 = ((size_t)ar0*FR + f0)*DIM + lcol;
  const size_t aoff1 = ((size_t)ar1*FR + f1)*DIM + lcol;
  const size_t boff  = (size_t)(h*64 + lrow)*DIM + lcol;

  // ---- phase 1: q2 tile (DIAG A-gather, K=768)
  f32x4 acc[2][4] = {};
  for (int k0 = 0; k0 < DIM; k0 += 32) {
    __syncthreads();
    gload_lds16(x    + aoff0 + k0, &As[w*16][0]);
    gload_lds16(x    + aoff1 + k0, &As[64 + w*16][0]);
    gload_lds16(WpqT + boff  + k0, &Bs[w*16][0]);
    __syncthreads();
    s16x8 af[2], bw[4];
    #pragma unroll
    for (int i = 0; i < 2; i++) af[i] = *(const s16x8*)&As[w*32 + i*16 + lq][quad*8];
    #pragma unroll
    for (int j = 0; j < 4; j++) bw[j] = *(const s16x8*)&Bs[j*16 + lq][quad*8];
    #pragma unroll
    for (int i = 0; i < 2; i++)
      #pragma unroll
      for (int j = 0; j < 4; j++)
        acc[i][j] = mfma16(af[i], bw[j], acc[i][j]);
  }

  // ---- park q2 tile in LDS bf16 (scale 0.125); rows are wave-local
  #pragma unroll
  for (int i = 0; i < 2; i++)
    #pragma unroll
    for (int r = 0; r < 4; r++) {
      int row = w*32 + i*16 + quad*4 + r;
      #pragma unroll
      for (int j = 0; j < 4; j++)
        q2s[row][j*16 + lq] = f2bf(acc[i][j][r] * 0.125f);
    }

  // ---- phase 2: qw tiles over c (12 x 64 cols), K=64 from q2s
  for (int ct = 0; ct < 12; ++ct) {
    f32x4 acc2[2][4] = {};
    #pragma unroll
    for (int k0 = 0; k0 < 64; k0 += 32) {
      __syncthreads();
      gload_lds16(Wpk + (size_t)(ct*64 + lrow)*DIM + h*HD + k0 + lcol, &Bs[w*16][0]);
      __syncthreads();
      s16x8 af[2], bw[4];
      #pragma unroll
      for (int i = 0; i < 2; i++)
        af[i] = *(const s16x8*)&q2s[w*32 + i*16 + lq][k0 + quad*8];
      #pragma unroll
      for (int j = 0; j < 4; j++) bw[j] = *(const s16x8*)&Bs[j*16 + lq][quad*8];
      #pragma unroll
      for (int i = 0; i < 2; i++)
        #pragma unroll
        for (int j = 0; j < 4; j++)
          acc2[i][j] = mfma16(af[i], bw[j], acc2[i][j]);
    }
    #pragma unroll
    for (int i = 0; i < 2; i++) {
      #pragma unroll
      for (int r = 0; r < 4; r++) {
        int row = by*128 + w*32 + i*16 + quad*4 + r;
        if (row < MTOT) {
          #pragma unroll
          for (int j = 0; j < 4; j++)
            qw[(size_t)row*(NH*DIM) + h*DIM + ct*64 + j*16 + lq] = f2bf(acc2[i][j][r]);
        }
      }
    }
  }
}

// ---------------------------------------------------------------------------
// Fused logits + softmax + x-aggregation. grid 1568 (2 t / block).
// R11 lesson: occupancy is the lever. This version drops the qw LDS staging
// entirely (Common-mistake #7: qw has ZERO intra-block reuse — each element
// feeds exactly one MFMA of one wave) and loads B fragments straight from
// global (L3-resident, 12 independent unrolled loads/wave). LDS 63 -> 27 KB
// -> 5 blocks/CU. x stays staged (reused by MFMA A + xa epilogue).
// K split across wave pairs; partials combined via 1.5 KB LDS (R11-proven).
// ---------------------------------------------------------------------------
__global__ __launch_bounds__(256)
void logits_sa(const ushort* __restrict__ qw, const ushort* __restrict__ x,
               float* __restrict__ attn2, ushort* __restrict__ xa)
{
  __shared__ ushort xs[2*8*792];       // 24.75 KB [tf][ch*264+cc]
  __shared__ float  part[2][2][8][12]; // [kh][tt][f][h] 1.5 KB
  __shared__ float  a_s[2][NH][FR];    // 0.75 KB
  const int tid = threadIdx.x;
  const int t0 = blockIdx.x * 2;

  #pragma unroll
  for (int r = 0; r < 6; ++r) {        // stage x: 2t*8f*96 vec8
    int id = r*256 + tid;
    int tf = id / 96, v8 = id % 96;
    int ch = v8 >> 5, cc = v8 & 31;
    s16x8 v = *(const s16x8*)(x + ((size_t)(t0 + (tf >> 3))*FR + (tf & 7))*DIM + v8*8);
    *(s16x8*)&xs[tf*792 + ch*264 + cc*8] = v;
  }
  __syncthreads();

  const int w = tid >> 6, lane = tid & 63;
  const int lq = lane & 15, quad = lane >> 4;
  const int tt = w & 1, kh = w >> 1;          // token, k-half per wave
  const int fr = lq & 7;                      // A row (rows 8-15 duplicate f)
  const int hc = (lq < 12) ? lq : 0;          // B col clamp
  const ushort* qwb = qw + (size_t)(t0 + tt)*(NH*DIM) + hc*DIM + quad*8;
  f32x4 acc = {};
  #pragma unroll
  for (int k = 0; k < 12; ++k) {
    int ks = kh*12 + k;
    int ch = ks >> 3, cc = (ks & 7) * 32;
    s16x8 a = *(const s16x8*)&xs[(tt*8 + fr)*792 + ch*264 + cc + quad*8];
    s16x8 b = *(const s16x8*)(qwb + ks*32);   // direct global (linear c = ks*32+quad*8)
    acc = mfma16(a, b, acc);
  }
  if (quad < 2 && lq < 12) {
    #pragma unroll
    for (int r = 0; r < 4; ++r)
      part[kh][tt][quad*4 + r][lq] = acc[r];
  }
  __syncthreads();

  // combine halves + softmax over f (waves 0-1 only; shfl_xor 16 pairs
  // quad0<->quad1 within lanes 0..31 exactly as the proven R11 version)
  if (kh == 0) {
    float l0 = part[0][tt][quad*4 + 0][hc] + part[1][tt][quad*4 + 0][hc];
    float l1 = part[0][tt][quad*4 + 1][hc] + part[1][tt][quad*4 + 1][hc];
    float l2 = part[0][tt][quad*4 + 2][hc] + part[1][tt][quad*4 + 2][hc];
    float l3 = part[0][tt][quad*4 + 3][hc] + part[1][tt][quad*4 + 3][hc];
    float m4 = fmaxf(fmaxf(l0, l1), fmaxf(l2, l3));
    float M = fmaxf(m4, __shfl_xor(m4, 16));
    float e0 = __expf(l0-M), e1 = __expf(l1-M);
    float e2 = __expf(l2-M), e3 = __expf(l3-M);
    float s4 = (e0+e1)+(e2+e3);
    float S = s4 + __shfl_xor(s4, 16);
    float inv = 1.0f / S;
    if (quad < 2 && lq < 12) {
      int gt = t0 + tt;
      int b = gt / SEQ, sI = gt % SEQ;
      float4 av; av.x = e0*inv; av.y = e1*inv; av.z = e2*inv; av.w = e3*inv;
      *(float4*)(attn2 + ((size_t)(b*NH + hc)*SEQ + sI)*FR + quad*4) = av;
      a_s[tt][hc][quad*4+0] = av.x; a_s[tt][hc][quad*4+1] = av.y;
      a_s[tt][hc][quad*4+2] = av.z; a_s[tt][hc][quad*4+3] = av.w;
    }
  }
  __syncthreads();

  // xa[t,c] = sum_f a_s[t][h(c)][f] * x[t,f,c]; x read from LDS
  if (tid < 192) {
    int tt2 = tid / 96, v8 = tid % 96;
    int ch = v8 >> 5, cc = v8 & 31;
    int h = v8 >> 3;
    float av[8] = {};
    #pragma unroll
    for (int f = 0; f < FR; ++f) {
      float a = a_s[tt2][h][f];
      s16x8 xv = *(const s16x8*)&xs[(tt2*8 + f)*792 + ch*264 + cc*8];
      #pragma unroll
      for (int e = 0; e < 8; ++e) av[e] += a * bf2f((ushort)xv[e]);
    }
    ushort4 o0, o1;
    o0.x = f2bf(av[0]); o0.y = f2bf(av[1]); o0.z = f2bf(av[2]); o0.w = f2bf(av[3]);
    o1.x = f2bf(av[4]); o1.y = f2bf(av[5]); o1.z = f2bf(av[6]); o1.w = f2bf(av[7]);
    ushort* op = xa + (size_t)(t0 + tt2)*DIM + v8*8;
    *(ushort4*)op = o0; *(ushort4*)(op + 4) = o1;
  }
}

// ---------------------------------------------------------------------------
// Stage 1, 32x32 MFMA, swapped operands (S^T = K.Q^T), in-register P.
// (unchanged from R2-verified version)
// ---------------------------------------------------------------------------
__global__ __launch_bounds__(256)
void stage1_mfma(const ushort* __restrict__ qbf, const ushort* __restrict__ kvbf,
                 const ushort* __restrict__ Vt, ushort* __restrict__ x)
{
  __shared__ ushort sh[208*64];   // 26624 B: K tile, then per-wave X transpose

  const int bh = blockIdx.x;   // 0..23
  const int f  = blockIdx.y;   // 0..7
  const int qt = blockIdx.z;   // 0..12
  const int b = bh / NH, h = bh % NH;
  const int tid = threadIdx.x;
  const int w = tid >> 6, lane = tid & 63;
  const int l31 = lane & 31, hl = lane >> 5;

  const ushort* kbase = kvbf + ((size_t)b*SEQ + f*NTOK)*(2*DIM) + h*HD;
  #pragma unroll
  for (int p = 0; p < 6; ++p) {
    const int c = w*6 + p;                         // 8-row chunk, rows < 192
    const int row = c*8 + (lane >> 3);
    const ushort* src = kbase + (size_t)row*(2*DIM)
                      + (((lane & 7) ^ (lane >> 3)) << 3);
    gload_lds16(src, &sh[c*512]);
  }
  { // rows 192..207: 192..195 from global, 196..207 zero (same swizzle)
    const int row = 192 + (tid >> 4);
    const int c4  = (tid & 15) << 2;
    ushort4 v; v.x = 0; v.y = 0; v.z = 0; v.w = 0;
    if (row < NTOK)
      v = *(const ushort4*)(kbase + (size_t)row*(2*DIM) + c4);
    *(ushort4*)&sh[row*64 + ((((c4 >> 3) ^ (row & 7)) << 3) | (c4 & 7))] = v;
  }

  int qrow = qt*128 + w*32 + l31; if (qrow > SEQ-1) qrow = SEQ-1;
  const ushort* qp = qbf + ((size_t)b*SEQ + qrow)*DIM + h*HD + hl*8;
  const s16x8 bq0 = *(const s16x8*)(qp);
  const s16x8 bq1 = *(const s16x8*)(qp + 16);
  const s16x8 bq2 = *(const s16x8*)(qp + 32);
  const s16x8 bq3 = *(const s16x8*)(qp + 48);

  __syncthreads();

  f32x16 acc[7];
  {
    f32x16 z = {};
    #pragma unroll
    for (int nt = 0; nt < 7; ++nt) acc[nt] = z;
  }
  const int sx = l31 & 7;
  #pragma unroll
  for (int nt = 0; nt < 7; ++nt) {
    const int rl = (nt == 6) ? (l31 & 15) : l31;   // keep tile-6 A-reads in bounds
    const int rbase = (nt*32 + rl)*64;
    acc[nt] = mfma32(*(const s16x8*)&sh[rbase + (((0 + hl) ^ sx) << 3)], bq0, acc[nt]);
    acc[nt] = mfma32(*(const s16x8*)&sh[rbase + (((2 + hl) ^ sx) << 3)], bq1, acc[nt]);
    acc[nt] = mfma32(*(const s16x8*)&sh[rbase + (((4 + hl) ^ sx) << 3)], bq2, acc[nt]);
    acc[nt] = mfma32(*(const s16x8*)&sh[rbase + (((6 + hl) ^ sx) << 3)], bq3, acc[nt]);
  }

  __syncthreads();   // all K reads done -> sh reusable for X transpose

  float s0 = 0.f, s1 = 0.f, s2 = 0.f, s3 = 0.f;
  #pragma unroll
  for (int nt = 0; nt < 7; ++nt) {
    #pragma unroll
    for (int g = 0; g < 16; ++g) {
      float e;
      if (nt == 6) {
        if (g < 4) { e = __expf(acc[6][g]); if (hl) e = 0.f; }  // n=192..195 only
        else e = 0.f;
      } else {
        e = __expf(acc[nt][g]);
      }
      acc[nt][g] = e;
      if ((g & 3) == 0) s0 += e; else if ((g & 3) == 1) s1 += e;
      else if ((g & 3) == 2) s2 += e; else s3 += e;
    }
  }
  float sum = (s0 + s1) + (s2 + s3);
  sum += __shfl_xor(sum, 32);
  const float sinv = 1.0f / sum;

  f32x16 o0, o1;
  { f32x16 z = {}; o0 = z; o1 = z; }
  const ushort* vb = Vt + ((size_t)((b*FR + f)*NH + h)) * (HD*224);
  const ushort* vr0 = vb + (size_t)l31*224 + hl*8;
  const ushort* vr1 = vr0 + 32*224;
  #pragma unroll
  for (int nt = 0; nt < 7; ++nt) {
    #pragma unroll
    for (int kh = 0; kh < 2; ++kh) {
      int w0 = cvtpk(acc[nt][8*kh+0], acc[nt][8*kh+1]);
      int w1 = cvtpk(acc[nt][8*kh+2], acc[nt][8*kh+3]);
      int w2 = cvtpk(acc[nt][8*kh+4], acc[nt][8*kh+5]);
      int w3 = cvtpk(acc[nt][8*kh+6], acc[nt][8*kh+7]);
      asm("v_permlane32_swap_b32 %0, %1" : "+v"(w0), "+v"(w2));
      asm("v_permlane32_swap_b32 %0, %1" : "+v"(w1), "+v"(w3));
      union { i32x4 i; s16x8 s; } u;
      u.i.x = w0; u.i.y = w1; u.i.z = w2; u.i.w = w3;
      const int ks = nt*2 + kh;
      const s16x8 va0 = *(const s16x8*)(vr0 + ks*16);
      const s16x8 va1 = *(const s16x8*)(vr1 + ks*16);
      o0 = mfma32(va0, u.s, o0);
      o1 = mfma32(va1, u.s, o1);
    }
  }

  ushort* XT = sh + w*2048;
  #pragma unroll
  for (int dt = 0; dt < 2; ++dt) {
    #pragma unroll
    for (int c = 0; c < 4; ++c) {
      #pragma unroll
      for (int rp = 0; rp < 2; ++rp) {
        const float lo = (dt ? o1[4*c + 2*rp]     : o0[4*c + 2*rp])     * sinv;
        const float hi = (dt ? o1[4*c + 2*rp + 1] : o0[4*c + 2*rp + 1]) * sinv;
        const int word = cvtpk(lo, hi);
        const int d = dt*32 + 8*c + 4*hl + 2*rp;
        *(uint*)&XT[l31*64 + (((d >> 3) ^ (l31 & 7)) << 3) + (d & 7)] = (uint)word;
      }
    }
  }
  #pragma unroll
  for (int it = 0; it < 4; ++it) {
    const int q = it*8 + (lane >> 3);
    const int g = lane & 7;
    s16x8 xv = *(const s16x8*)&XT[q*64 + ((g ^ (q & 7)) << 3)];
    const int s = qt*128 + w*32 + q;
    if (s < SEQ) {
      ushort* xp = x + (((size_t)b*SEQ + s)*FR + f)*DIM + h*HD + g*8;
      *(s16x8*)xp = xv;
    }
  }
}

// ---------------------------------------------------------------------------
// Workspace (ushort units; ~123 MB used; harness memsets ~268 MB of ws):
//  xbf | kvbf | qbf | xqbf (Vt alias) | xkbf (xa alias) |
//  WqT | WkvT | WpqT | WprT | Wpk_bf | Wpv_bf | WcombT | qw (57.8 MB full)
// ---------------------------------------------------------------------------
extern "C" void kernel_launch(void* const* d_in, const int* in_sizes, int n_in,
                              void* d_out, int out_size, void* d_ws, size_t ws_size,
                              hipStream_t stream) {
  const float* xq    = (const float*)d_in[0];
  const float* xk    = (const float*)d_in[1];
  const float* Wq    = (const float*)d_in[2];
  const float* Wkv   = (const float*)d_in[3];
  const float* Wpq   = (const float*)d_in[4];
  const float* Wpkv  = (const float*)d_in[5];
  const float* Wproj = (const float*)d_in[6];
  const float* bproj = (const float*)d_in[7];

  float* out   = (float*)d_out;
  float* attn2 = out + (size_t)MTOT*DIM;

  ushort* ws     = (ushort*)d_ws;
  ushort* xbf    = ws;
  ushort* kvbf   = xbf + (size_t)MTOT*FR*DIM;
  ushort* qbf    = kvbf + (size_t)MTOT*2*DIM;
  ushort* xqbf   = qbf + (size_t)MTOT*DIM;
  ushort* xkbf   = xqbf + (size_t)MTOT*DIM;
  ushort* Vt     = xqbf;                        // alias (dead post-proj)
  ushort* xa     = xkbf;                        // alias (dead post-proj)
  ushort* WqT    = xkbf + (size_t)MTOT*DIM;
  ushort* WkvT   = WqT  + (size_t)DIM*DIM;
  ushort* WpqT   = WkvT + (size_t)2*DIM*DIM;
  ushort* WprT   = WpqT + (size_t)DIM*DIM;
  ushort* Wpk_bf = WprT + (size_t)DIM*DIM;
  ushort* Wpv_bf = Wpk_bf + (size_t)DIM*DIM;
  ushort* WcombT = Wpv_bf + (size_t)DIM*DIM;
  ushort* qw     = WcombT + (size_t)DIM*DIM;    // [3136][12][768] bf16, 57.8 MB

  dim3 blk(256);
  const int n4 = MTOT*DIM/4;

  cvt_all<<<dim3(4704 + 1152 + 1152), blk, 0, stream>>>(
      xq, xk, xqbf, xkbf, Wq, Wkv, Wpq, Wproj, Wpkv,
      WqT, WkvT, WpqT, WprT, Wpk_bf, Wpv_bf, n4);

  // WcombT[n][k] = sum_m Wproj[m][n]*Wpv[k][m]  (fused z+out projection)
  gemm64<false,true><<<dim3(12, 6), blk, 0, stream>>>(
      WprT, Wpv_bf, WcombT, nullptr, DIM, DIM, 1.0f);

  proj_pair<<<dim3(18, (MTOT+127)/128), blk, 0, stream>>>(
      xqbf, xkbf, WqT, WkvT, qbf, kvbf);
  vtrans<<<dim3(BDIM*FR*NH), blk, 0, stream>>>(kvbf, Vt);
  stage1_mfma<<<dim3(BDIM*NH, FR, (SEQ+127)/128), blk, 0, stream>>>(qbf, kvbf, Vt, xbf);

  // fused q2 + qw (replaces q2 gemm + qwgemm; no q2bf round-trip)
  q2qw<<<dim3(12, 25), blk, 0, stream>>>(xbf, WpqT, Wpk_bf, qw);

  logits_sa<<<dim3(MTOT/2), blk, 0, stream>>>(qw, xbf, attn2, xa);

  // out = xa @ Wcomb + bproj  (128x64 tiles -> 300 blocks, R10-proven)
  gemm64<true,false><<<dim3(12, (MTOT+127)/128), blk, 0, stream>>>(
      xa, WcombT, out, bproj, MTOT, DIM, 1.0f);
}

// Round 13
// 236.035 us; speedup vs baseline: 1.0705x; 1.0007x over previous
//
#include <hip/hip_runtime.h>

#define BDIM 2
#define SEQ  1568
#define DIM  768
#define NH   12
#define FR   8
#define NTOK 196
#define HD   64
#define MTOT (BDIM*SEQ)   // 3136 token rows
#define M2   (MTOT*FR)    // 25088 (t,f) rows

typedef __attribute__((ext_vector_type(8))) short s16x8;
typedef __attribute__((ext_vector_type(4))) float f32x4;
typedef __attribute__((ext_vector_type(16))) float f32x16;
typedef __attribute__((ext_vector_type(4))) int i32x4;

static __device__ __forceinline__ float bf2f(ushort u) {
  return __uint_as_float(((unsigned)u) << 16);
}
static __device__ __forceinline__ ushort f2bf(float f) {
  unsigned u = __float_as_uint(f);
  unsigned r = (u + 0x7fffu + ((u >> 16) & 1u)) >> 16;
  return (ushort)r;
}
static __device__ __forceinline__ f32x4 mfma16(s16x8 a, s16x8 b, f32x4 c) {
  return __builtin_amdgcn_mfma_f32_16x16x32_bf16(a, b, c, 0, 0, 0);
}
static __device__ __forceinline__ f32x16 mfma32(s16x8 a, s16x8 b, f32x16 c) {
  return __builtin_amdgcn_mfma_f32_32x32x16_bf16(a, b, c, 0, 0, 0);
}
static __device__ __forceinline__ int cvtpk(float lo, float hi) {
  int r;
  asm("v_cvt_pk_bf16_f32 %0, %1, %2" : "=v"(r) : "v"(lo), "v"(hi));
  return r;
}
static __device__ __forceinline__ void gload_lds16(const ushort* g, ushort* l) {
  __builtin_amdgcn_global_load_lds(
      (const __attribute__((address_space(1))) void*)g,
      (__attribute__((address_space(3))) void*)l, 16, 0, 0);
}

// ---------------------------------------------------------------------------
// Fused convert: inputs -> bf16, 4 weights transposed -> bf16, and straight
// bf16 copies of the Wpkv halves (Wpk_bf, Wpv_bf) for the qw / Wcomb paths.
// grid: 4704 input + 1152 transpose (nx24 x ky12 x wid4) + 1152 straight.
// ---------------------------------------------------------------------------
__global__ __launch_bounds__(256)
void cvt_all(const float* __restrict__ xq, const float* __restrict__ xk,
             ushort* __restrict__ xqbf, ushort* __restrict__ xkbf,
             const float* __restrict__ Wq, const float* __restrict__ Wkv,
             const float* __restrict__ Wpq, const float* __restrict__ Wproj,
             const float* __restrict__ Wpkv,
             ushort* __restrict__ WqT, ushort* __restrict__ WkvT,
             ushort* __restrict__ WpqT, ushort* __restrict__ WprT,
             ushort* __restrict__ Wpk_bf, ushort* __restrict__ Wpv_bf,
             int n4) {
  __shared__ float T[64][65];
  const int blk = blockIdx.x;
  const int tid = threadIdx.x;

  if (blk < 4704) {             // input conversion
    int i = blk*256 + tid;
    const float* src; ushort* dst; int j;
    if (i < n4)        { src = xq; dst = xqbf; j = i; }
    else               { src = xk; dst = xkbf; j = i - n4; }
    float4 v = ((const float4*)src)[j];
    ushort4 o; o.x = f2bf(v.x); o.y = f2bf(v.y); o.z = f2bf(v.z); o.w = f2bf(v.w);
    ((ushort4*)dst)[j] = o;
    return;
  }

  if (blk < 5856) {             // weight transpose (4 weights)
    int idx = blk - 4704;
    const int wid = idx / 288; idx %= 288;
    const int ky = idx / 24;
    const int nx = idx % 24;
    const float* W; ushort* WT; int N;
    switch (wid) {
      case 0: W = Wq;    WT = WqT;   N = DIM;   break;
      case 1: W = Wkv;   WT = WkvT;  N = 2*DIM; break;
      case 2: W = Wpq;   WT = WpqT;  N = DIM;   break;
      default: W = Wproj; WT = WprT; N = DIM;   break;
    }
    if (nx >= N/64) return;
    #pragma unroll
    for (int it = 0; it < 4; it++) {
      int id2 = it*256 + tid;
      int r = id2 >> 4, c4 = (id2 & 15) << 2;
      float4 v = *(const float4*)&W[(size_t)(ky*64 + r)*N + nx*64 + c4];
      T[r][c4+0] = v.x; T[r][c4+1] = v.y; T[r][c4+2] = v.z; T[r][c4+3] = v.w;
    }
    __syncthreads();
    #pragma unroll
    for (int it = 0; it < 4; it++) {
      int id2 = it*256 + tid;
      int n = id2 >> 4, k4 = (id2 & 15) << 2;
      ushort4 o;
      o.x = f2bf(T[k4+0][n]); o.y = f2bf(T[k4+1][n]);
      o.z = f2bf(T[k4+2][n]); o.w = f2bf(T[k4+3][n]);
      *(ushort4*)&WT[(size_t)(nx*64 + n)*DIM + ky*64 + k4] = o;
    }
    return;
  }

  // straight bf16 copies of Wpkv halves: Wpk_bf / Wpv_bf [768][768]
  {
    int id2 = blk - 5856;            // 0..1151
    int half = id2 / 576;
    int e = (id2 % 576)*256 + tid;   // float4 index within 768x768
    int r = e / 192;
    int c4 = (e % 192) * 4;
    float4 v = *(const float4*)&Wpkv[(size_t)r*(2*DIM) + half*DIM + c4];
    ushort4 o; o.x = f2bf(v.x); o.y = f2bf(v.y); o.z = f2bf(v.z); o.w = f2bf(v.w);
    ushort* dst = half ? Wpv_bf : Wpk_bf;
    *(ushort4*)&dst[(size_t)r*DIM + c4] = o;
  }
}

// Vt[(b,f,h)][64][224] bf16, zero-padded n>=196. grid = 192
__global__ __launch_bounds__(256)
void vtrans(const ushort* __restrict__ kvbf, ushort* __restrict__ Vt) {
  __shared__ ushort Vl[NTOK][72];
  const int x = blockIdx.x;
  const int h = x % NH, f = (x / NH) % FR, b = x / (NH*FR);
  const int tid = threadIdx.x;
  for (int idx = tid; idx < NTOK*16; idx += 256) {
    int n = idx >> 4, c4 = (idx & 15) << 2;
    const ushort* p = kvbf + (size_t)(b*SEQ + f*NTOK + n)*(2*DIM) + DIM + h*HD + c4;
    *(ushort4*)&Vl[n][c4] = *(const ushort4*)p;
  }
  __syncthreads();
  ushort* vb = Vt + (size_t)x * (HD*224);
  for (int idx = tid; idx < 64*56; idx += 256) {
    int d = idx / 56, n4 = (idx % 56) << 2;
    ushort4 o;
    o.x = (n4+0 < NTOK) ? Vl[n4+0][d] : (ushort)0;
    o.y = (n4+1 < NTOK) ? Vl[n4+1][d] : (ushort)0;
    o.z = (n4+2 < NTOK) ? Vl[n4+2][d] : (ushort)0;
    o.w = (n4+3 < NTOK) ? Vl[n4+3][d] : (ushort)0;
    *(ushort4*)&vb[(size_t)d*224 + n4] = o;
  }
}

// ---------------------------------------------------------------------------
// Merged q+kv projection, 128x128 tiles. grid (18, 25) = 450 blocks >= CU
// count (R10-proven best config).
// bx<6: qbf = 0.125*(xq@Wq) cols bx*128; else kvbf = xk@Wkv cols (bx-6)*128.
// ---------------------------------------------------------------------------
__global__ __launch_bounds__(256)
void proj_pair(const ushort* __restrict__ xqbf, const ushort* __restrict__ xkbf,
               const ushort* __restrict__ WqT, const ushort* __restrict__ WkvT,
               ushort* __restrict__ qbf, ushort* __restrict__ kvbf)
{
  __shared__ ushort As[128][32];
  __shared__ ushort Bs[128][32];
  const int bx = blockIdx.x, by = blockIdx.y;
  const ushort* A; const ushort* Bt; ushort* C; int N, col0; float scale;
  if (bx < 6) { A = xqbf; Bt = WqT;  C = qbf;  N = DIM;   col0 = bx*128;     scale = 0.125f; }
  else        { A = xkbf; Bt = WkvT; C = kvbf; N = 2*DIM; col0 = (bx-6)*128; scale = 1.0f; }

  const int tid = threadIdx.x;
  const int w = tid >> 6, lane = tid & 63;
  const int lq = lane & 15, quad = lane >> 4;
  const int wr = (w >> 1) * 64, wc = (w & 1) * 64;
  const int lrow = tid >> 2, lcol = (tid & 3) << 3;

  int ar0 = by*128 + lrow;       if (ar0 > MTOT-1) ar0 = MTOT-1;
  int ar1 = by*128 + 64 + lrow;  if (ar1 > MTOT-1) ar1 = MTOT-1;
  const size_t aoff0 = (size_t)ar0*DIM + lcol;
  const size_t aoff1 = (size_t)ar1*DIM + lcol;
  const size_t boff0 = (size_t)(col0 + lrow)*DIM + lcol;
  const size_t boff1 = (size_t)(col0 + 64 + lrow)*DIM + lcol;

  f32x4 acc[4][4] = {};
  for (int k0 = 0; k0 < DIM; k0 += 32) {
    __syncthreads();
    gload_lds16(A  + aoff0 + k0, &As[w*16][0]);
    gload_lds16(A  + aoff1 + k0, &As[64 + w*16][0]);
    gload_lds16(Bt + boff0 + k0, &Bs[w*16][0]);
    gload_lds16(Bt + boff1 + k0, &Bs[64 + w*16][0]);
    __syncthreads();
    s16x8 af[4], bw[4];
    #pragma unroll
    for (int i = 0; i < 4; i++) af[i] = *(const s16x8*)&As[wr + i*16 + lq][quad*8];
    #pragma unroll
    for (int j = 0; j < 4; j++) bw[j] = *(const s16x8*)&Bs[wc + j*16 + lq][quad*8];
    #pragma unroll
    for (int i = 0; i < 4; i++)
      #pragma unroll
      for (int j = 0; j < 4; j++)
        acc[i][j] = mfma16(af[i], bw[j], acc[i][j]);
  }

  #pragma unroll
  for (int i = 0; i < 4; i++) {
    #pragma unroll
    for (int r = 0; r < 4; r++) {
      int row = by*128 + wr + i*16 + quad*4 + r;
      if (row < MTOT) {
        #pragma unroll
        for (int j = 0; j < 4; j++)
          C[(size_t)row*N + col0 + wc + j*16 + lq] = f2bf(acc[i][j][r] * scale);
      }
    }
  }
}

// ---------------------------------------------------------------------------
// 128x64-tile GEMM (R8-proven). grid (N/64, ceil(M/128)). K=768.
// 300 blocks for the M=3136 out-proj keeps grid >= CU count (R9 lesson).
// BF16OUT: C is ushort bf16; else float.
// ---------------------------------------------------------------------------
template<bool BIAS, bool BF16OUT>
__global__ __launch_bounds__(256)
void gemm64(const ushort* __restrict__ A, const ushort* __restrict__ Bt,
            void* __restrict__ Cv, const float* __restrict__ bias,
            int M, int N, float scale)
{
  __shared__ ushort As[128][32];
  __shared__ ushort Bs[64][32];
  const int bx = blockIdx.x, by = blockIdx.y;
  const int tid = threadIdx.x;
  const int w = tid >> 6, lane = tid & 63;
  const int lq = lane & 15, quad = lane >> 4;
  const int lrow = tid >> 2, lcol = (tid & 3) << 3;
  const int col0 = bx*64;

  int ar0 = by*128 + lrow;       if (ar0 > M-1) ar0 = M-1;
  int ar1 = by*128 + 64 + lrow;  if (ar1 > M-1) ar1 = M-1;
  const size_t aoff0 = (size_t)ar0*DIM + lcol;
  const size_t aoff1 = (size_t)ar1*DIM + lcol;
  const size_t boff = (size_t)(col0 + lrow)*DIM + lcol;

  f32x4 acc[2][4] = {};
  for (int k0 = 0; k0 < DIM; k0 += 32) {
    __syncthreads();
    gload_lds16(A  + aoff0 + k0, &As[w*16][0]);
    gload_lds16(A  + aoff1 + k0, &As[64 + w*16][0]);
    gload_lds16(Bt + boff  + k0, &Bs[w*16][0]);
    __syncthreads();
    s16x8 af[2], bw[4];
    #pragma unroll
    for (int i = 0; i < 2; i++) af[i] = *(const s16x8*)&As[w*32 + i*16 + lq][quad*8];
    #pragma unroll
    for (int j = 0; j < 4; j++) bw[j] = *(const s16x8*)&Bs[j*16 + lq][quad*8];
    #pragma unroll
    for (int i = 0; i < 2; i++)
      #pragma unroll
      for (int j = 0; j < 4; j++)
        acc[i][j] = mfma16(af[i], bw[j], acc[i][j]);
  }

  #pragma unroll
  for (int i = 0; i < 2; i++) {
    #pragma unroll
    for (int r = 0; r < 4; r++) {
      int row = by*128 + w*32 + i*16 + quad*4 + r;
      if (row < M) {
        #pragma unroll
        for (int j = 0; j < 4; j++) {
          int col = col0 + j*16 + lq;
          float v = acc[i][j][r] * scale;
          if (BIAS) v += bias[col];
          if (BF16OUT) ((ushort*)Cv)[(size_t)row*N + col] = f2bf(v);
          else         ((float*)Cv)[(size_t)row*N + col] = v;
        }
      }
    }
  }
}

// ---------------------------------------------------------------------------
// FUSED q2 + qw kernel. grid (12 = head, 25 Mtiles).
// Phase 1: q2 tile = 0.125*(x_diag @ Wpq) cols h*64..+63  (K=768, DIAG gather)
//          -> parked in LDS q2s[128][72] bf16 (same-wave rows only).
// Phase 2: qw[row][h][c] = sum_dd q2[row][dd]*Wpk[c][h*64+dd] for c in 12
//          64-wide tiles (K=64, Bs restaged per 32-chunk, 1 gload/step).
// ---------------------------------------------------------------------------
__global__ __launch_bounds__(256)
void q2qw(const ushort* __restrict__ x, const ushort* __restrict__ WpqT,
          const ushort* __restrict__ Wpk, ushort* __restrict__ qw)
{
  __shared__ ushort As[128][32];
  __shared__ ushort Bs[64][32];
  __shared__ ushort q2s[128][72];
  const int h = blockIdx.x, by = blockIdx.y;
  const int tid = threadIdx.x;
  const int w = tid >> 6, lane = tid & 63;
  const int lq = lane & 15, quad = lane >> 4;
  const int lrow = tid >> 2, lcol = (tid & 3) << 3;

  int ar0 = by*128 + lrow;       if (ar0 > MTOT-1) ar0 = MTOT-1;
  int ar1 = by*128 + 64 + lrow;  if (ar1 > MTOT-1) ar1 = MTOT-1;
  const int f0 = (ar0 % SEQ) / NTOK, f1 = (ar1 % SEQ) / NTOK;
  const size_t aoff0 = ((size_t)ar0*FR + f0)*DIM + lcol;
  const size_t aoff1 = ((size_t)ar1*FR + f1)*DIM + lcol;
  const size_t boff  = (size_t)(h*64 + lrow)*DIM + lcol;

  // ---- phase 1: q2 tile (DIAG A-gather, K=768)
  f32x4 acc[2][4] = {};
  for (int k0 = 0; k0 < DIM; k0 += 32) {
    __syncthreads();
    gload_lds16(x    + aoff0 + k0, &As[w*16][0]);
    gload_lds16(x    + aoff1 + k0, &As[64 + w*16][0]);
    gload_lds16(WpqT + boff  + k0, &Bs[w*16][0]);
    __syncthreads();
    s16x8 af[2], bw[4];
    #pragma unroll
    for (int i = 0; i < 2; i++) af[i] = *(const s16x8*)&As[w*32 + i*16 + lq][quad*8];
    #pragma unroll
    for (int j = 0; j < 4; j++) bw[j] = *(const s16x8*)&Bs[j*16 + lq][quad*8];
    #pragma unroll
    for (int i = 0; i < 2; i++)
      #pragma unroll
      for (int j = 0; j < 4; j++)
        acc[i][j] = mfma16(af[i], bw[j], acc[i][j]);
  }

  // ---- park q2 tile in LDS bf16 (scale 0.125); rows are wave-local
  #pragma unroll
  for (int i = 0; i < 2; i++)
    #pragma unroll
    for (int r = 0; r < 4; r++) {
      int row = w*32 + i*16 + quad*4 + r;
      #pragma unroll
      for (int j = 0; j < 4; j++)
        q2s[row][j*16 + lq] = f2bf(acc[i][j][r] * 0.125f);
    }

  // ---- phase 2: qw tiles over c (12 x 64 cols), K=64 from q2s
  for (int ct = 0; ct < 12; ++ct) {
    f32x4 acc2[2][4] = {};
    #pragma unroll
    for (int k0 = 0; k0 < 64; k0 += 32) {
      __syncthreads();
      gload_lds16(Wpk + (size_t)(ct*64 + lrow)*DIM + h*HD + k0 + lcol, &Bs[w*16][0]);
      __syncthreads();
      s16x8 af[2], bw[4];
      #pragma unroll
      for (int i = 0; i < 2; i++)
        af[i] = *(const s16x8*)&q2s[w*32 + i*16 + lq][k0 + quad*8];
      #pragma unroll
      for (int j = 0; j < 4; j++) bw[j] = *(const s16x8*)&Bs[j*16 + lq][quad*8];
      #pragma unroll
      for (int i = 0; i < 2; i++)
        #pragma unroll
        for (int j = 0; j < 4; j++)
          acc2[i][j] = mfma16(af[i], bw[j], acc2[i][j]);
    }
    #pragma unroll
    for (int i = 0; i < 2; i++) {
      #pragma unroll
      for (int r = 0; r < 4; r++) {
        int row = by*128 + w*32 + i*16 + quad*4 + r;
        if (row < MTOT) {
          #pragma unroll
          for (int j = 0; j < 4; j++)
            qw[(size_t)row*(NH*DIM) + h*DIM + ct*64 + j*16 + lq] = f2bf(acc2[i][j][r]);
        }
      }
    }
  }
}

// ---------------------------------------------------------------------------
// Fused logits + softmax + x-aggregation. grid 1568 (2 t / block).
// (R12 version: x staged in LDS; qw consumed direct-from-global — zero reuse.)
// ---------------------------------------------------------------------------
__global__ __launch_bounds__(256)
void logits_sa(const ushort* __restrict__ qw, const ushort* __restrict__ x,
               float* __restrict__ attn2, ushort* __restrict__ xa)
{
  __shared__ ushort xs[2*8*792];       // 24.75 KB [tf][ch*264+cc]
  __shared__ float  part[2][2][8][12]; // [kh][tt][f][h] 1.5 KB
  __shared__ float  a_s[2][NH][FR];    // 0.75 KB
  const int tid = threadIdx.x;
  const int t0 = blockIdx.x * 2;

  #pragma unroll
  for (int r = 0; r < 6; ++r) {        // stage x: 2t*8f*96 vec8
    int id = r*256 + tid;
    int tf = id / 96, v8 = id % 96;
    int ch = v8 >> 5, cc = v8 & 31;
    s16x8 v = *(const s16x8*)(x + ((size_t)(t0 + (tf >> 3))*FR + (tf & 7))*DIM + v8*8);
    *(s16x8*)&xs[tf*792 + ch*264 + cc*8] = v;
  }
  __syncthreads();

  const int w = tid >> 6, lane = tid & 63;
  const int lq = lane & 15, quad = lane >> 4;
  const int tt = w & 1, kh = w >> 1;          // token, k-half per wave
  const int fr = lq & 7;                      // A row (rows 8-15 duplicate f)
  const int hc = (lq < 12) ? lq : 0;          // B col clamp
  const ushort* qwb = qw + (size_t)(t0 + tt)*(NH*DIM) + hc*DIM + quad*8;
  f32x4 acc = {};
  #pragma unroll
  for (int k = 0; k < 12; ++k) {
    int ks = kh*12 + k;
    int ch = ks >> 3, cc = (ks & 7) * 32;
    s16x8 a = *(const s16x8*)&xs[(tt*8 + fr)*792 + ch*264 + cc + quad*8];
    s16x8 b = *(const s16x8*)(qwb + ks*32);   // direct global (linear c = ks*32+quad*8)
    acc = mfma16(a, b, acc);
  }
  if (quad < 2 && lq < 12) {
    #pragma unroll
    for (int r = 0; r < 4; ++r)
      part[kh][tt][quad*4 + r][lq] = acc[r];
  }
  __syncthreads();

  // combine halves + softmax over f (waves 0-1 only)
  if (kh == 0) {
    float l0 = part[0][tt][quad*4 + 0][hc] + part[1][tt][quad*4 + 0][hc];
    float l1 = part[0][tt][quad*4 + 1][hc] + part[1][tt][quad*4 + 1][hc];
    float l2 = part[0][tt][quad*4 + 2][hc] + part[1][tt][quad*4 + 2][hc];
    float l3 = part[0][tt][quad*4 + 3][hc] + part[1][tt][quad*4 + 3][hc];
    float m4 = fmaxf(fmaxf(l0, l1), fmaxf(l2, l3));
    float M = fmaxf(m4, __shfl_xor(m4, 16));
    float e0 = __expf(l0-M), e1 = __expf(l1-M);
    float e2 = __expf(l2-M), e3 = __expf(l3-M);
    float s4 = (e0+e1)+(e2+e3);
    float S = s4 + __shfl_xor(s4, 16);
    float inv = 1.0f / S;
    if (quad < 2 && lq < 12) {
      int gt = t0 + tt;
      int b = gt / SEQ, sI = gt % SEQ;
      float4 av; av.x = e0*inv; av.y = e1*inv; av.z = e2*inv; av.w = e3*inv;
      *(float4*)(attn2 + ((size_t)(b*NH + hc)*SEQ + sI)*FR + quad*4) = av;
      a_s[tt][hc][quad*4+0] = av.x; a_s[tt][hc][quad*4+1] = av.y;
      a_s[tt][hc][quad*4+2] = av.z; a_s[tt][hc][quad*4+3] = av.w;
    }
  }
  __syncthreads();

  // xa[t,c] = sum_f a_s[t][h(c)][f] * x[t,f,c]; x read from LDS
  if (tid < 192) {
    int tt2 = tid / 96, v8 = tid % 96;
    int ch = v8 >> 5, cc = v8 & 31;
    int h = v8 >> 3;
    float av[8] = {};
    #pragma unroll
    for (int f = 0; f < FR; ++f) {
      float a = a_s[tt2][h][f];
      s16x8 xv = *(const s16x8*)&xs[(tt2*8 + f)*792 + ch*264 + cc*8];
      #pragma unroll
      for (int e = 0; e < 8; ++e) av[e] += a * bf2f((ushort)xv[e]);
    }
    ushort4 o0, o1;
    o0.x = f2bf(av[0]); o0.y = f2bf(av[1]); o0.z = f2bf(av[2]); o0.w = f2bf(av[3]);
    o1.x = f2bf(av[4]); o1.y = f2bf(av[5]); o1.z = f2bf(av[6]); o1.w = f2bf(av[7]);
    ushort* op = xa + (size_t)(t0 + tt2)*DIM + v8*8;
    *(ushort4*)op = o0; *(ushort4*)(op + 4) = o1;
  }
}

// ---------------------------------------------------------------------------
// Stage 1, 32x32 MFMA, swapped operands (S^T = K.Q^T), in-register P.
// R13: STREAMED K-tiles. Deferred normalization (sinv at epilogue) makes PV
// linear in unnormalized exp(S), so each 32-key tile is computed, exp'd,
// converted (cvtpk+permlane), and fed to PV immediately — one live f32x16
// instead of acc[7] (-96 VGPR -> ~2x occupancy). Identical arithmetic order:
// nt ascending for both the s0..s3 sums and the o0/o1 MFMA chains.
// ---------------------------------------------------------------------------
__global__ __launch_bounds__(256)
void stage1_mfma(const ushort* __restrict__ qbf, const ushort* __restrict__ kvbf,
                 const ushort* __restrict__ Vt, ushort* __restrict__ x)
{
  __shared__ ushort sh[208*64];   // 26624 B: K tile, then per-wave X transpose

  const int bh = blockIdx.x;   // 0..23
  const int f  = blockIdx.y;   // 0..7
  const int qt = blockIdx.z;   // 0..12
  const int b = bh / NH, h = bh % NH;
  const int tid = threadIdx.x;
  const int w = tid >> 6, lane = tid & 63;
  const int l31 = lane & 31, hl = lane >> 5;

  const ushort* kbase = kvbf + ((size_t)b*SEQ + f*NTOK)*(2*DIM) + h*HD;
  #pragma unroll
  for (int p = 0; p < 6; ++p) {
    const int c = w*6 + p;                         // 8-row chunk, rows < 192
    const int row = c*8 + (lane >> 3);
    const ushort* src = kbase + (size_t)row*(2*DIM)
                      + (((lane & 7) ^ (lane >> 3)) << 3);
    gload_lds16(src, &sh[c*512]);
  }
  { // rows 192..207: 192..195 from global, 196..207 zero (same swizzle)
    const int row = 192 + (tid >> 4);
    const int c4  = (tid & 15) << 2;
    ushort4 v; v.x = 0; v.y = 0; v.z = 0; v.w = 0;
    if (row < NTOK)
      v = *(const ushort4*)(kbase + (size_t)row*(2*DIM) + c4);
    *(ushort4*)&sh[row*64 + ((((c4 >> 3) ^ (row & 7)) << 3) | (c4 & 7))] = v;
  }

  int qrow = qt*128 + w*32 + l31; if (qrow > SEQ-1) qrow = SEQ-1;
  const ushort* qp = qbf + ((size_t)b*SEQ + qrow)*DIM + h*HD + hl*8;
  const s16x8 bq0 = *(const s16x8*)(qp);
  const s16x8 bq1 = *(const s16x8*)(qp + 16);
  const s16x8 bq2 = *(const s16x8*)(qp + 32);
  const s16x8 bq3 = *(const s16x8*)(qp + 48);

  __syncthreads();

  // ---- streamed: per 32-key tile {QK^T, exp+sum, P-frag build, PV}
  const int sx = l31 & 7;
  const ushort* vb = Vt + ((size_t)((b*FR + f)*NH + h)) * (HD*224);
  const ushort* vr0 = vb + (size_t)l31*224 + hl*8;
  const ushort* vr1 = vr0 + 32*224;
  f32x16 o0, o1;
  { f32x16 z = {}; o0 = z; o1 = z; }
  float s0 = 0.f, s1 = 0.f, s2 = 0.f, s3 = 0.f;

  #pragma unroll
  for (int nt = 0; nt < 7; ++nt) {
    const int rl = (nt == 6) ? (l31 & 15) : l31;   // keep tile-6 A-reads in bounds
    const int rbase = (nt*32 + rl)*64;
    f32x16 c;
    { f32x16 z = {}; c = z; }
    c = mfma32(*(const s16x8*)&sh[rbase + (((0 + hl) ^ sx) << 3)], bq0, c);
    c = mfma32(*(const s16x8*)&sh[rbase + (((2 + hl) ^ sx) << 3)], bq1, c);
    c = mfma32(*(const s16x8*)&sh[rbase + (((4 + hl) ^ sx) << 3)], bq2, c);
    c = mfma32(*(const s16x8*)&sh[rbase + (((6 + hl) ^ sx) << 3)], bq3, c);

    // exp (no max-subtraction; logits bounded, validated r8) + masking
    #pragma unroll
    for (int g = 0; g < 16; ++g) {
      float e;
      if (nt == 6) {
        if (g < 4) { e = __expf(c[g]); if (hl) e = 0.f; }  // n=192..195 only
        else e = 0.f;
      } else {
        e = __expf(c[g]);
      }
      c[g] = e;
      if ((g & 3) == 0) s0 += e; else if ((g & 3) == 1) s1 += e;
      else if ((g & 3) == 2) s2 += e; else s3 += e;
    }

    // P-frag build (cvtpk + permlane32_swap, D.hi <-> S.lo) + PV
    #pragma unroll
    for (int kh = 0; kh < 2; ++kh) {
      int w0 = cvtpk(c[8*kh+0], c[8*kh+1]);
      int w1 = cvtpk(c[8*kh+2], c[8*kh+3]);
      int w2 = cvtpk(c[8*kh+4], c[8*kh+5]);
      int w3 = cvtpk(c[8*kh+6], c[8*kh+7]);
      asm("v_permlane32_swap_b32 %0, %1" : "+v"(w0), "+v"(w2));
      asm("v_permlane32_swap_b32 %0, %1" : "+v"(w1), "+v"(w3));
      union { i32x4 i; s16x8 s; } u;
      u.i.x = w0; u.i.y = w1; u.i.z = w2; u.i.w = w3;
      const int ks = nt*2 + kh;
      const s16x8 va0 = *(const s16x8*)(vr0 + ks*16);
      const s16x8 va1 = *(const s16x8*)(vr1 + ks*16);
      o0 = mfma32(va0, u.s, o0);
      o1 = mfma32(va1, u.s, o1);
    }
  }

  float sum = (s0 + s1) + (s2 + s3);
  sum += __shfl_xor(sum, 32);
  const float sinv = 1.0f / sum;

  __syncthreads();   // all K reads done -> sh reusable for X transpose

  ushort* XT = sh + w*2048;
  #pragma unroll
  for (int dt = 0; dt < 2; ++dt) {
    #pragma unroll
    for (int c = 0; c < 4; ++c) {
      #pragma unroll
      for (int rp = 0; rp < 2; ++rp) {
        const float lo = (dt ? o1[4*c + 2*rp]     : o0[4*c + 2*rp])     * sinv;
        const float hi = (dt ? o1[4*c + 2*rp + 1] : o0[4*c + 2*rp + 1]) * sinv;
        const int word = cvtpk(lo, hi);
        const int d = dt*32 + 8*c + 4*hl + 2*rp;
        *(uint*)&XT[l31*64 + (((d >> 3) ^ (l31 & 7)) << 3) + (d & 7)] = (uint)word;
      }
    }
  }
  #pragma unroll
  for (int it = 0; it < 4; ++it) {
    const int q = it*8 + (lane >> 3);
    const int g = lane & 7;
    s16x8 xv = *(const s16x8*)&XT[q*64 + ((g ^ (q & 7)) << 3)];
    const int s = qt*128 + w*32 + q;
    if (s < SEQ) {
      ushort* xp = x + (((size_t)b*SEQ + s)*FR + f)*DIM + h*HD + g*8;
      *(s16x8*)xp = xv;
    }
  }
}

// ---------------------------------------------------------------------------
// Workspace (ushort units; ~123 MB used; harness memsets ~268 MB of ws):
//  xbf | kvbf | qbf | xqbf (Vt alias) | xkbf (xa alias) |
//  WqT | WkvT | WpqT | WprT | Wpk_bf | Wpv_bf | WcombT | qw (57.8 MB full)
// ---------------------------------------------------------------------------
extern "C" void kernel_launch(void* const* d_in, const int* in_sizes, int n_in,
                              void* d_out, int out_size, void* d_ws, size_t ws_size,
                              hipStream_t stream) {
  const float* xq    = (const float*)d_in[0];
  const float* xk    = (const float*)d_in[1];
  const float* Wq    = (const float*)d_in[2];
  const float* Wkv   = (const float*)d_in[3];
  const float* Wpq   = (const float*)d_in[4];
  const float* Wpkv  = (const float*)d_in[5];
  const float* Wproj = (const float*)d_in[6];
  const float* bproj = (const float*)d_in[7];

  float* out   = (float*)d_out;
  float* attn2 = out + (size_t)MTOT*DIM;

  ushort* ws     = (ushort*)d_ws;
  ushort* xbf    = ws;
  ushort* kvbf   = xbf + (size_t)MTOT*FR*DIM;
  ushort* qbf    = kvbf + (size_t)MTOT*2*DIM;
  ushort* xqbf   = qbf + (size_t)MTOT*DIM;
  ushort* xkbf   = xqbf + (size_t)MTOT*DIM;
  ushort* Vt     = xqbf;                        // alias (dead post-proj)
  ushort* xa     = xkbf;                        // alias (dead post-proj)
  ushort* WqT    = xkbf + (size_t)MTOT*DIM;
  ushort* WkvT   = WqT  + (size_t)DIM*DIM;
  ushort* WpqT   = WkvT + (size_t)2*DIM*DIM;
  ushort* WprT   = WpqT + (size_t)DIM*DIM;
  ushort* Wpk_bf = WprT + (size_t)DIM*DIM;
  ushort* Wpv_bf = Wpk_bf + (size_t)DIM*DIM;
  ushort* WcombT = Wpv_bf + (size_t)DIM*DIM;
  ushort* qw     = WcombT + (size_t)DIM*DIM;    // [3136][12][768] bf16, 57.8 MB

  dim3 blk(256);
  const int n4 = MTOT*DIM/4;

  cvt_all<<<dim3(4704 + 1152 + 1152), blk, 0, stream>>>(
      xq, xk, xqbf, xkbf, Wq, Wkv, Wpq, Wproj, Wpkv,
      WqT, WkvT, WpqT, WprT, Wpk_bf, Wpv_bf, n4);

  // WcombT[n][k] = sum_m Wproj[m][n]*Wpv[k][m]  (fused z+out projection)
  gemm64<false,true><<<dim3(12, 6), blk, 0, stream>>>(
      WprT, Wpv_bf, WcombT, nullptr, DIM, DIM, 1.0f);

  proj_pair<<<dim3(18, (MTOT+127)/128), blk, 0, stream>>>(
      xqbf, xkbf, WqT, WkvT, qbf, kvbf);
  vtrans<<<dim3(BDIM*FR*NH), blk, 0, stream>>>(kvbf, Vt);
  stage1_mfma<<<dim3(BDIM*NH, FR, (SEQ+127)/128), blk, 0, stream>>>(qbf, kvbf, Vt, xbf);

  // fused q2 + qw (replaces q2 gemm + qwgemm; no q2bf round-trip)
  q2qw<<<dim3(12, 25), blk, 0, stream>>>(xbf, WpqT, Wpk_bf, qw);

  logits_sa<<<dim3(MTOT/2), blk, 0, stream>>>(qw, xbf, attn2, xa);

  // out = xa @ Wcomb + bproj  (128x64 tiles -> 300 blocks, R10-proven)
  gemm64<true,false><<<dim3(12, (MTOT+127)/128), blk, 0, stream>>>(
      xa, WcombT, out, bproj, MTOT, DIM, 1.0f);
}